// Round 2
// baseline (1236.249 us; speedup 1.0000x reference)
//
#include <hip/hip_runtime.h>
#include <hip/hip_bf16.h>
#include <math.h>

#define N_NODES 50000
#define N_EDGES 640000
#define IN_DIM 5
#define HID 128
#define NGRAPH 512

__device__ __forceinline__ float vget(const float4& v, int k) {
  return k == 0 ? v.x : k == 1 ? v.y : k == 2 ? v.z : v.w;
}

// ---------------- CSR build ----------------
__global__ void count_edges_k(const int* __restrict__ dst, int* __restrict__ counts) {
  int e = blockIdx.x * blockDim.x + threadIdx.x;
  if (e < N_EDGES) atomicAdd(&counts[dst[e]], 1);
}

__global__ __launch_bounds__(1024) void scan_k(const int* __restrict__ counts,
                                               int* __restrict__ row_ptr,
                                               int* __restrict__ fill_off) {
  __shared__ int sums[1024];
  const int CH = 49;  // ceil(50000/1024)
  int t = threadIdx.x;
  int base = t * CH;
  int s = 0;
  for (int j = 0; j < CH; ++j) { int i = base + j; if (i < N_NODES) s += counts[i]; }
  sums[t] = s;
  __syncthreads();
  for (int off = 1; off < 1024; off <<= 1) {
    int v = (t >= off) ? sums[t - off] : 0;
    __syncthreads();
    sums[t] += v;
    __syncthreads();
  }
  int run = sums[t] - s;  // exclusive prefix of this thread's chunk
  for (int j = 0; j < CH; ++j) {
    int i = base + j;
    if (i < N_NODES) { row_ptr[i] = run; fill_off[i] = run; run += counts[i]; }
  }
  if (t == 1023) row_ptr[N_NODES] = sums[1023];
}

__global__ void fill_edges_k(const int* __restrict__ src, const int* __restrict__ dst,
                             int* __restrict__ fill_off, int* __restrict__ esrc) {
  int e = blockIdx.x * blockDim.x + threadIdx.x;
  if (e < N_EDGES) {
    int d = dst[e];
    int pos = atomicAdd(&fill_off[d], 1);
    esrc[pos] = src[e];
  }
}

// ---------------- Layer 0 projection (IN_DIM=5) ----------------
__global__ void proj0_k(const float* __restrict__ x, const float* __restrict__ Wrel,
                        const float* __restrict__ bias, const float* __restrict__ Wroot,
                        float* __restrict__ Z, float* __restrict__ OUT) {
  int idx = blockIdx.x * blockDim.x + threadIdx.x;  // node*128 + c
  if (idx >= N_NODES * HID) return;
  int i = idx >> 7, c = idx & 127;
  float xr[IN_DIM];
#pragma unroll
  for (int k = 0; k < IN_DIM; ++k) xr[k] = x[i * IN_DIM + k];
  float zr = 0.f, zo = bias[c];
#pragma unroll
  for (int k = 0; k < IN_DIM; ++k) {
    zr = fmaf(xr[k], Wrel[k * HID + c], zr);
    zo = fmaf(xr[k], Wroot[k * HID + c], zo);
  }
  Z[idx] = zr;
  OUT[idx] = zo;
}

// ---------------- GEMM for layers 1,2 (A f32 [N,128], W f32 [128,128]) ----------------
// grid: (row_tiles, 4). gy 0,1 -> W_rel -> Z ; gy 2,3 -> W_root(+bias) -> OUT
__global__ __launch_bounds__(256) void gemm_k(const float* __restrict__ A,
                                              const float* __restrict__ Wrel,
                                              const float* __restrict__ Wroot,
                                              const float* __restrict__ bias,
                                              float* __restrict__ Z,
                                              float* __restrict__ OUT) {
  __shared__ float As[64][68];  // [row][k], padded
  __shared__ float Bs[64][64];  // [k][col]
  int tid = threadIdx.x;
  int tx = tid & 15, ty = tid >> 4;
  int r0 = blockIdx.x * 64;
  int gy = blockIdx.y;
  bool isRoot = gy >= 2;
  int c0 = (gy & 1) * 64;
  const float* W = isRoot ? Wroot : Wrel;
  float acc[4][4] = {{0.f}};

  for (int kk = 0; kk < HID; kk += 64) {
#pragma unroll
    for (int it = 0; it < 4; ++it) {
      int idx = it * 256 + tid;
      int row = idx >> 4;  // 0..63  (A-row / B-k)
      int q = idx & 15;    // float4 slot
      int grow = r0 + row;
      float4 v = make_float4(0.f, 0.f, 0.f, 0.f);
      if (grow < N_NODES) v = *(const float4*)(A + (size_t)grow * HID + kk + q * 4);
      *(float4*)&As[row][q * 4] = v;
      float4 w4 = *(const float4*)(W + (size_t)(kk + row) * HID + c0 + q * 4);
      *(float4*)&Bs[row][q * 4] = w4;
    }
    __syncthreads();
#pragma unroll
    for (int k = 0; k < 64; k += 4) {
      float4 af[4];
#pragma unroll
      for (int i = 0; i < 4; ++i) af[i] = *(const float4*)&As[ty * 4 + i][k];
#pragma unroll
      for (int k2 = 0; k2 < 4; ++k2) {
        float4 b4 = *(const float4*)&Bs[k + k2][tx * 4];
#pragma unroll
        for (int i = 0; i < 4; ++i) {
          float av = vget(af[i], k2);
          acc[i][0] = fmaf(av, b4.x, acc[i][0]);
          acc[i][1] = fmaf(av, b4.y, acc[i][1]);
          acc[i][2] = fmaf(av, b4.z, acc[i][2]);
          acc[i][3] = fmaf(av, b4.w, acc[i][3]);
        }
      }
    }
    __syncthreads();
  }

  float* dstp = isRoot ? OUT : Z;
#pragma unroll
  for (int i = 0; i < 4; ++i) {
    int row = r0 + ty * 4 + i;
    if (row < N_NODES) {
      float4 v = make_float4(acc[i][0], acc[i][1], acc[i][2], acc[i][3]);
      int c = c0 + tx * 4;
      if (isRoot) {
        v.x += bias[c + 0];
        v.y += bias[c + 1];
        v.z += bias[c + 2];
        v.w += bias[c + 3];
      }
      *(float4*)(dstp + (size_t)row * HID + c) = v;
    }
  }
}

// ---------------- Edge aggregation: OUT[i] = act(OUT[i] + sum_e Z[esrc[e]]) ----------------
__global__ __launch_bounds__(256) void agg_k(const float* __restrict__ Z,
                                             const int* __restrict__ row_ptr,
                                             const int* __restrict__ esrc,
                                             float* __restrict__ OUT, int do_relu) {
  int wave = threadIdx.x >> 6;
  int lane = threadIdx.x & 63;
  int node = blockIdx.x * 4 + wave;
  if (node >= N_NODES) return;
  int beg = row_ptr[node], end = row_ptr[node + 1];
  float2 acc = *(const float2*)&OUT[(size_t)node * HID + lane * 2];
  for (int e = beg; e < end; ++e) {
    int s = esrc[e];
    float2 z = *(const float2*)&Z[(size_t)s * HID + lane * 2];
    acc.x += z.x;
    acc.y += z.y;
  }
  if (do_relu) { acc.x = fmaxf(acc.x, 0.f); acc.y = fmaxf(acc.y, 0.f); }
  *(float2*)&OUT[(size_t)node * HID + lane * 2] = acc;
}

// ---------------- Mean pool (atomics) ----------------
__global__ __launch_bounds__(256) void pool_k(const float* __restrict__ H,
                                              const int* __restrict__ batch,
                                              float* __restrict__ pool, int* __restrict__ cnt) {
  int wave = threadIdx.x >> 6;
  int lane = threadIdx.x & 63;
  int node = blockIdx.x * 4 + wave;
  if (node >= N_NODES) return;
  int g = batch[node];
  float2 h = *(const float2*)&H[(size_t)node * HID + lane * 2];
  atomicAdd(&pool[(size_t)g * HID + lane * 2 + 0], h.x);
  atomicAdd(&pool[(size_t)g * HID + lane * 2 + 1], h.y);
  if (lane == 0) atomicAdd(&cnt[g], 1);
}

// ---------------- Final: sigmoid(pool/cnt @ Wlin + b) ----------------
__global__ __launch_bounds__(256) void final_k(const float* __restrict__ pool,
                                               const int* __restrict__ cnt,
                                               const float* __restrict__ Wlin,
                                               const float* __restrict__ blin,
                                               float* __restrict__ out) {
  int wave = threadIdx.x >> 6;
  int lane = threadIdx.x & 63;
  int g = blockIdx.x * 4 + wave;
  if (g >= NGRAPH) return;
  float2 p = *(const float2*)&pool[(size_t)g * HID + lane * 2];
  float v = p.x * Wlin[lane * 2 + 0] + p.y * Wlin[lane * 2 + 1];
#pragma unroll
  for (int off = 32; off; off >>= 1) v += __shfl_down(v, off, 64);
  if (lane == 0) {
    float c = (float)cnt[g];
    if (c < 1.f) c = 1.f;
    float logit = v / c + blin[0];
    out[g] = 1.f / (1.f + expf(-logit));
  }
}

extern "C" void kernel_launch(void* const* d_in, const int* in_sizes, int n_in,
                              void* d_out, int out_size, void* d_ws, size_t ws_size,
                              hipStream_t stream) {
  const float* x      = (const float*)d_in[0];
  const int*   ei     = (const int*)d_in[1];
  const int*   batch  = (const int*)d_in[2];
  const float* Wrel0  = (const float*)d_in[3];
  const float* brel0  = (const float*)d_in[4];
  const float* Wroot0 = (const float*)d_in[5];
  const float* Wrel1  = (const float*)d_in[6];
  const float* brel1  = (const float*)d_in[7];
  const float* Wroot1 = (const float*)d_in[8];
  const float* Wrel2  = (const float*)d_in[9];
  const float* brel2  = (const float*)d_in[10];
  const float* Wroot2 = (const float*)d_in[11];
  const float* Wlin   = (const float*)d_in[12];
  const float* blin   = (const float*)d_in[13];
  float* out = (float*)d_out;
  const int* srcp = ei;
  const int* dstp = ei + N_EDGES;

  char* ws = (char*)d_ws;
  size_t off = 0;
  auto alloc = [&](size_t b) { size_t o = off; off += (b + 255) & ~(size_t)255; return o; };
  float* Z    = (float*)(ws + alloc(sizeof(float) * N_NODES * HID));
  float* OUTA = (float*)(ws + alloc(sizeof(float) * N_NODES * HID));
  float* OUTB = (float*)(ws + alloc(sizeof(float) * N_NODES * HID));
  int* row_ptr  = (int*)(ws + alloc(sizeof(int) * (N_NODES + 1)));
  int* esrc     = (int*)(ws + alloc(sizeof(int) * N_EDGES));
  int* fill_off = (int*)(ws + alloc(sizeof(int) * N_NODES));
  size_t zero_base = off;
  int* counts  = (int*)(ws + alloc(sizeof(int) * N_NODES));
  float* pool  = (float*)(ws + alloc(sizeof(float) * NGRAPH * HID));
  int* cnt     = (int*)(ws + alloc(sizeof(int) * NGRAPH));
  size_t zero_len = off - zero_base;

  hipMemsetAsync(ws + zero_base, 0, zero_len, stream);

  count_edges_k<<<(N_EDGES + 255) / 256, 256, 0, stream>>>(dstp, counts);
  scan_k<<<1, 1024, 0, stream>>>(counts, row_ptr, fill_off);
  fill_edges_k<<<(N_EDGES + 255) / 256, 256, 0, stream>>>(srcp, dstp, fill_off, esrc);

  // Layer 0
  proj0_k<<<(N_NODES * HID + 255) / 256, 256, 0, stream>>>(x, Wrel0, brel0, Wroot0, Z, OUTA);
  agg_k<<<(N_NODES + 3) / 4, 256, 0, stream>>>(Z, row_ptr, esrc, OUTA, 1);
  // Layer 1
  gemm_k<<<dim3((N_NODES + 63) / 64, 4), 256, 0, stream>>>(OUTA, Wrel1, Wroot1, brel1, Z, OUTB);
  agg_k<<<(N_NODES + 3) / 4, 256, 0, stream>>>(Z, row_ptr, esrc, OUTB, 1);
  // Layer 2
  gemm_k<<<dim3((N_NODES + 63) / 64, 4), 256, 0, stream>>>(OUTB, Wrel2, Wroot2, brel2, Z, OUTA);
  agg_k<<<(N_NODES + 3) / 4, 256, 0, stream>>>(Z, row_ptr, esrc, OUTA, 0);

  pool_k<<<(N_NODES + 3) / 4, 256, 0, stream>>>(OUTA, batch, pool, cnt);
  final_k<<<(NGRAPH + 3) / 4, 256, 0, stream>>>(pool, cnt, Wlin, blin, out);
}

// Round 3
// 720.452 us; speedup vs baseline: 1.7159x; 1.7159x over previous
//
#include <hip/hip_runtime.h>
#include <hip/hip_bf16.h>
#include <math.h>

#define N_NODES 50000
#define N_EDGES 640000
#define IN_DIM 5
#define HID 128
#define NGRAPH 512

__device__ __forceinline__ float vget(const float4& v, int k) {
  return k == 0 ? v.x : k == 1 ? v.y : k == 2 ? v.z : v.w;
}

// ---------------- CSR build ----------------
__global__ void count_edges_k(const int* __restrict__ dst, int* __restrict__ counts) {
  int e = blockIdx.x * blockDim.x + threadIdx.x;
  if (e < N_EDGES) atomicAdd(&counts[dst[e]], 1);
}

__global__ __launch_bounds__(1024) void scan_k(const int* __restrict__ counts,
                                               int* __restrict__ row_ptr,
                                               int* __restrict__ fill_off) {
  __shared__ int sums[1024];
  const int CH = 49;  // ceil(50000/1024)
  int t = threadIdx.x;
  int base = t * CH;
  int s = 0;
  for (int j = 0; j < CH; ++j) { int i = base + j; if (i < N_NODES) s += counts[i]; }
  sums[t] = s;
  __syncthreads();
  for (int off = 1; off < 1024; off <<= 1) {
    int v = (t >= off) ? sums[t - off] : 0;
    __syncthreads();
    sums[t] += v;
    __syncthreads();
  }
  int run = sums[t] - s;  // exclusive prefix of this thread's chunk
  for (int j = 0; j < CH; ++j) {
    int i = base + j;
    if (i < N_NODES) { row_ptr[i] = run; fill_off[i] = run; run += counts[i]; }
  }
  if (t == 1023) row_ptr[N_NODES] = sums[1023];
}

__global__ void fill_edges_k(const int* __restrict__ src, const int* __restrict__ dst,
                             int* __restrict__ fill_off, int* __restrict__ esrc) {
  int e = blockIdx.x * blockDim.x + threadIdx.x;
  if (e < N_EDGES) {
    int d = dst[e];
    int pos = atomicAdd(&fill_off[d], 1);
    esrc[pos] = src[e];
  }
}

// ---------------- Layer 0 projection (IN_DIM=5) ----------------
__global__ void proj0_k(const float* __restrict__ x, const float* __restrict__ Wrel,
                        const float* __restrict__ bias, const float* __restrict__ Wroot,
                        float* __restrict__ Z, float* __restrict__ OUT) {
  int idx = blockIdx.x * blockDim.x + threadIdx.x;  // node*128 + c
  if (idx >= N_NODES * HID) return;
  int i = idx >> 7, c = idx & 127;
  float xr[IN_DIM];
#pragma unroll
  for (int k = 0; k < IN_DIM; ++k) xr[k] = x[i * IN_DIM + k];
  float zr = 0.f, zo = bias[c];
#pragma unroll
  for (int k = 0; k < IN_DIM; ++k) {
    zr = fmaf(xr[k], Wrel[k * HID + c], zr);
    zo = fmaf(xr[k], Wroot[k * HID + c], zo);
  }
  Z[idx] = zr;
  OUT[idx] = zo;
}

// ---------------- GEMM for layers 1,2 ----------------
// One block = 64 A-rows. A staged to LDS ONCE; loop over 4 output tiles
// (rel c0, rel c64, root c0, root c64), staging one 64x64 W tile per k-step.
// __launch_bounds__(256,4): cap VGPR<=128 (round-2 profile: VGPR=256 + ~700MB
// spill traffic at unrestricted pressure). unroll 2 keeps live ranges short.
__global__ __launch_bounds__(256, 4) void gemm_k(const float* __restrict__ A,
                                                 const float* __restrict__ Wrel,
                                                 const float* __restrict__ Wroot,
                                                 const float* __restrict__ bias,
                                                 float* __restrict__ Z,
                                                 float* __restrict__ OUT) {
  __shared__ float As[64][132];  // 64 rows x 128 k, pad +4
  __shared__ float Ws[64][68];   // 64 k x 64 cols, pad +4
  int tid = threadIdx.x;
  int tx = tid & 15, ty = tid >> 4;
  int r0 = blockIdx.x * 64;

  // Stage A tile once: 64 rows x 128 cols = 2048 float4
#pragma unroll
  for (int it = 0; it < 8; ++it) {
    int idx = it * 256 + tid;
    int row = idx >> 5;  // 32 float4 per row
    int q = idx & 31;
    int grow = r0 + row;
    float4 v = make_float4(0.f, 0.f, 0.f, 0.f);
    if (grow < N_NODES) v = *(const float4*)(A + (size_t)grow * HID + q * 4);
    *(float4*)&As[row][q * 4] = v;
  }

  for (int t = 0; t < 4; ++t) {
    const float* W = (t < 2) ? Wrel : Wroot;
    int c0 = (t & 1) * 64;
    float acc[4][4];
    if (t >= 2) {
      float4 b4 = *(const float4*)(bias + c0 + tx * 4);
#pragma unroll
      for (int i = 0; i < 4; ++i) {
        acc[i][0] = b4.x; acc[i][1] = b4.y; acc[i][2] = b4.z; acc[i][3] = b4.w;
      }
    } else {
#pragma unroll
      for (int i = 0; i < 4; ++i)
        for (int j = 0; j < 4; ++j) acc[i][j] = 0.f;
    }

    for (int kk = 0; kk < HID; kk += 64) {
      __syncthreads();  // As ready (t=0,kk=0) / previous compute done with Ws
#pragma unroll
      for (int it = 0; it < 4; ++it) {
        int idx = it * 256 + tid;
        int r = idx >> 4;  // 16 float4 per row
        int q = idx & 15;
        *(float4*)&Ws[r][q * 4] = *(const float4*)(W + (size_t)(kk + r) * HID + c0 + q * 4);
      }
      __syncthreads();
#pragma unroll 2
      for (int k = 0; k < 64; k += 4) {
        float4 af[4];
#pragma unroll
        for (int i = 0; i < 4; ++i) af[i] = *(const float4*)&As[ty * 4 + i][kk + k];
#pragma unroll
        for (int k2 = 0; k2 < 4; ++k2) {
          float4 w4 = *(const float4*)&Ws[k + k2][tx * 4];
#pragma unroll
          for (int i = 0; i < 4; ++i) {
            float av = vget(af[i], k2);
            acc[i][0] = fmaf(av, w4.x, acc[i][0]);
            acc[i][1] = fmaf(av, w4.y, acc[i][1]);
            acc[i][2] = fmaf(av, w4.z, acc[i][2]);
            acc[i][3] = fmaf(av, w4.w, acc[i][3]);
          }
        }
      }
    }

    float* dstp = (t < 2) ? Z : OUT;
#pragma unroll
    for (int i = 0; i < 4; ++i) {
      int row = r0 + ty * 4 + i;
      if (row < N_NODES) {
        float4 v = make_float4(acc[i][0], acc[i][1], acc[i][2], acc[i][3]);
        *(float4*)(dstp + (size_t)row * HID + c0 + tx * 4) = v;
      }
    }
  }
}

// ---------------- Edge aggregation: OUT[i] = act(OUT[i] + sum_e Z[esrc[e]]) ----------------
__global__ __launch_bounds__(256) void agg_k(const float* __restrict__ Z,
                                             const int* __restrict__ row_ptr,
                                             const int* __restrict__ esrc,
                                             float* __restrict__ OUT, int do_relu) {
  int wave = threadIdx.x >> 6;
  int lane = threadIdx.x & 63;
  int node = blockIdx.x * 4 + wave;
  if (node >= N_NODES) return;
  int beg = row_ptr[node], end = row_ptr[node + 1];
  float2 acc = *(const float2*)&OUT[(size_t)node * HID + lane * 2];
  for (int e = beg; e < end; ++e) {
    int s = esrc[e];
    float2 z = *(const float2*)&Z[(size_t)s * HID + lane * 2];
    acc.x += z.x;
    acc.y += z.y;
  }
  if (do_relu) { acc.x = fmaxf(acc.x, 0.f); acc.y = fmaxf(acc.y, 0.f); }
  *(float2*)&OUT[(size_t)node * HID + lane * 2] = acc;
}

// ---------------- Mean pool (atomics) ----------------
__global__ __launch_bounds__(256) void pool_k(const float* __restrict__ H,
                                              const int* __restrict__ batch,
                                              float* __restrict__ pool, int* __restrict__ cnt) {
  int wave = threadIdx.x >> 6;
  int lane = threadIdx.x & 63;
  int node = blockIdx.x * 4 + wave;
  if (node >= N_NODES) return;
  int g = batch[node];
  float2 h = *(const float2*)&H[(size_t)node * HID + lane * 2];
  atomicAdd(&pool[(size_t)g * HID + lane * 2 + 0], h.x);
  atomicAdd(&pool[(size_t)g * HID + lane * 2 + 1], h.y);
  if (lane == 0) atomicAdd(&cnt[g], 1);
}

// ---------------- Final: sigmoid(pool/cnt @ Wlin + b) ----------------
__global__ __launch_bounds__(256) void final_k(const float* __restrict__ pool,
                                               const int* __restrict__ cnt,
                                               const float* __restrict__ Wlin,
                                               const float* __restrict__ blin,
                                               float* __restrict__ out) {
  int wave = threadIdx.x >> 6;
  int lane = threadIdx.x & 63;
  int g = blockIdx.x * 4 + wave;
  if (g >= NGRAPH) return;
  float2 p = *(const float2*)&pool[(size_t)g * HID + lane * 2];
  float v = p.x * Wlin[lane * 2 + 0] + p.y * Wlin[lane * 2 + 1];
#pragma unroll
  for (int off = 32; off; off >>= 1) v += __shfl_down(v, off, 64);
  if (lane == 0) {
    float c = (float)cnt[g];
    if (c < 1.f) c = 1.f;
    float logit = v / c + blin[0];
    out[g] = 1.f / (1.f + expf(-logit));
  }
}

extern "C" void kernel_launch(void* const* d_in, const int* in_sizes, int n_in,
                              void* d_out, int out_size, void* d_ws, size_t ws_size,
                              hipStream_t stream) {
  const float* x      = (const float*)d_in[0];
  const int*   ei     = (const int*)d_in[1];
  const int*   batch  = (const int*)d_in[2];
  const float* Wrel0  = (const float*)d_in[3];
  const float* brel0  = (const float*)d_in[4];
  const float* Wroot0 = (const float*)d_in[5];
  const float* Wrel1  = (const float*)d_in[6];
  const float* brel1  = (const float*)d_in[7];
  const float* Wroot1 = (const float*)d_in[8];
  const float* Wrel2  = (const float*)d_in[9];
  const float* brel2  = (const float*)d_in[10];
  const float* Wroot2 = (const float*)d_in[11];
  const float* Wlin   = (const float*)d_in[12];
  const float* blin   = (const float*)d_in[13];
  float* out = (float*)d_out;
  const int* srcp = ei;
  const int* dstp = ei + N_EDGES;

  char* ws = (char*)d_ws;
  size_t off = 0;
  auto alloc = [&](size_t b) { size_t o = off; off += (b + 255) & ~(size_t)255; return o; };
  float* Z    = (float*)(ws + alloc(sizeof(float) * N_NODES * HID));
  float* OUTA = (float*)(ws + alloc(sizeof(float) * N_NODES * HID));
  float* OUTB = (float*)(ws + alloc(sizeof(float) * N_NODES * HID));
  int* row_ptr  = (int*)(ws + alloc(sizeof(int) * (N_NODES + 1)));
  int* esrc     = (int*)(ws + alloc(sizeof(int) * N_EDGES));
  int* fill_off = (int*)(ws + alloc(sizeof(int) * N_NODES));
  size_t zero_base = off;
  int* counts  = (int*)(ws + alloc(sizeof(int) * N_NODES));
  float* pool  = (float*)(ws + alloc(sizeof(float) * NGRAPH * HID));
  int* cnt     = (int*)(ws + alloc(sizeof(int) * NGRAPH));
  size_t zero_len = off - zero_base;

  hipMemsetAsync(ws + zero_base, 0, zero_len, stream);

  count_edges_k<<<(N_EDGES + 255) / 256, 256, 0, stream>>>(dstp, counts);
  scan_k<<<1, 1024, 0, stream>>>(counts, row_ptr, fill_off);
  fill_edges_k<<<(N_EDGES + 255) / 256, 256, 0, stream>>>(srcp, dstp, fill_off, esrc);

  // Layer 0
  proj0_k<<<(N_NODES * HID + 255) / 256, 256, 0, stream>>>(x, Wrel0, brel0, Wroot0, Z, OUTA);
  agg_k<<<(N_NODES + 3) / 4, 256, 0, stream>>>(Z, row_ptr, esrc, OUTA, 1);
  // Layer 1
  gemm_k<<<(N_NODES + 63) / 64, 256, 0, stream>>>(OUTA, Wrel1, Wroot1, brel1, Z, OUTB);
  agg_k<<<(N_NODES + 3) / 4, 256, 0, stream>>>(Z, row_ptr, esrc, OUTB, 1);
  // Layer 2
  gemm_k<<<(N_NODES + 63) / 64, 256, 0, stream>>>(OUTB, Wrel2, Wroot2, brel2, Z, OUTA);
  agg_k<<<(N_NODES + 3) / 4, 256, 0, stream>>>(Z, row_ptr, esrc, OUTA, 0);

  pool_k<<<(N_NODES + 3) / 4, 256, 0, stream>>>(OUTA, batch, pool, cnt);
  final_k<<<(NGRAPH + 3) / 4, 256, 0, stream>>>(pool, cnt, Wlin, blin, out);
}

// Round 4
// 614.322 us; speedup vs baseline: 2.0124x; 1.1728x over previous
//
#include <hip/hip_runtime.h>
#include <hip/hip_bf16.h>
#include <math.h>

#define N_NODES 50000
#define N_EDGES 640000
#define IN_DIM 5
#define HID 128
#define NGRAPH 512
#define SCAN_NBLK ((N_NODES + 255) / 256)  // 196

__device__ __forceinline__ float vget(const float4& v, int k) {
  return k == 0 ? v.x : k == 1 ? v.y : k == 2 ? v.z : v.w;
}

// ---------------- CSR build ----------------
__global__ void count_edges_k(const int* __restrict__ dst, int* __restrict__ counts) {
  int e = blockIdx.x * blockDim.x + threadIdx.x;
  if (e < N_EDGES) atomicAdd(&counts[dst[e]], 1);
}

// 196 blocks x 256: per-block sum of counts
__global__ __launch_bounds__(256) void partial_k(const int* __restrict__ counts,
                                                 int* __restrict__ bsum) {
  int t = threadIdx.x;
  int i = blockIdx.x * 256 + t;
  int v = (i < N_NODES) ? counts[i] : 0;
#pragma unroll
  for (int off = 32; off; off >>= 1) v += __shfl_down(v, off, 64);
  __shared__ int ws[4];
  if ((t & 63) == 0) ws[t >> 6] = v;
  __syncthreads();
  if (t == 0) bsum[blockIdx.x] = ws[0] + ws[1] + ws[2] + ws[3];
}

// single small block: exclusive-scan the 196 block sums
__global__ __launch_bounds__(256) void scanb_k(const int* __restrict__ bsum,
                                               int* __restrict__ boff,
                                               int* __restrict__ row_ptr) {
  __shared__ int s[256];
  int t = threadIdx.x;
  int v = (t < SCAN_NBLK) ? bsum[t] : 0;
  s[t] = v;
  __syncthreads();
#pragma unroll
  for (int off = 1; off < 256; off <<= 1) {
    int u = (t >= off) ? s[t - off] : 0;
    __syncthreads();
    s[t] += u;
    __syncthreads();
  }
  if (t < SCAN_NBLK) boff[t] = s[t] - v;  // exclusive
  if (t == 255) row_ptr[N_NODES] = s[255];
}

// 196 blocks: local exclusive scan + block offset -> row_ptr / fill_off
__global__ __launch_bounds__(256) void write_scan_k(const int* __restrict__ counts,
                                                    const int* __restrict__ boff,
                                                    int* __restrict__ row_ptr,
                                                    int* __restrict__ fill_off) {
  __shared__ int s[256];
  int t = threadIdx.x;
  int i = blockIdx.x * 256 + t;
  int c = (i < N_NODES) ? counts[i] : 0;
  s[t] = c;
  __syncthreads();
#pragma unroll
  for (int off = 1; off < 256; off <<= 1) {
    int u = (t >= off) ? s[t - off] : 0;
    __syncthreads();
    s[t] += u;
    __syncthreads();
  }
  int excl = s[t] - c + boff[blockIdx.x];
  if (i < N_NODES) {
    row_ptr[i] = excl;
    fill_off[i] = excl;
  }
}

__global__ void fill_edges_k(const int* __restrict__ src, const int* __restrict__ dst,
                             int* __restrict__ fill_off, int* __restrict__ esrc) {
  int e = blockIdx.x * blockDim.x + threadIdx.x;
  if (e < N_EDGES) {
    int d = dst[e];
    int pos = atomicAdd(&fill_off[d], 1);
    esrc[pos] = src[e];
  }
}

// ---------------- Layer 0 projection (IN_DIM=5) ----------------
__global__ void proj0_k(const float* __restrict__ x, const float* __restrict__ Wrel,
                        const float* __restrict__ bias, const float* __restrict__ Wroot,
                        float* __restrict__ Z, float* __restrict__ OUT) {
  int idx = blockIdx.x * blockDim.x + threadIdx.x;  // node*128 + c
  if (idx >= N_NODES * HID) return;
  int i = idx >> 7, c = idx & 127;
  float xr[IN_DIM];
#pragma unroll
  for (int k = 0; k < IN_DIM; ++k) xr[k] = x[i * IN_DIM + k];
  float zr = 0.f, zo = bias[c];
#pragma unroll
  for (int k = 0; k < IN_DIM; ++k) {
    zr = fmaf(xr[k], Wrel[k * HID + c], zr);
    zo = fmaf(xr[k], Wroot[k * HID + c], zo);
  }
  Z[idx] = zr;
  OUT[idx] = zo;
}

// ---------------- GEMM for layers 1,2 ----------------
// One block = 64 A-rows. A staged to LDS once; 4 output tiles (rel/root x c0/c64).
// __launch_bounds__(256,4) caps VGPR<=128 (round-2: VGPR=256 caused ~700MB spill).
__global__ __launch_bounds__(256, 4) void gemm_k(const float* __restrict__ A,
                                                 const float* __restrict__ Wrel,
                                                 const float* __restrict__ Wroot,
                                                 const float* __restrict__ bias,
                                                 float* __restrict__ Z,
                                                 float* __restrict__ OUT) {
  __shared__ float As[64][132];
  __shared__ float Ws[64][68];
  int tid = threadIdx.x;
  int tx = tid & 15, ty = tid >> 4;
  int r0 = blockIdx.x * 64;

#pragma unroll
  for (int it = 0; it < 8; ++it) {
    int idx = it * 256 + tid;
    int row = idx >> 5;
    int q = idx & 31;
    int grow = r0 + row;
    float4 v = make_float4(0.f, 0.f, 0.f, 0.f);
    if (grow < N_NODES) v = *(const float4*)(A + (size_t)grow * HID + q * 4);
    *(float4*)&As[row][q * 4] = v;
  }

  for (int t = 0; t < 4; ++t) {
    const float* W = (t < 2) ? Wrel : Wroot;
    int c0 = (t & 1) * 64;
    float acc[4][4];
    if (t >= 2) {
      float4 b4 = *(const float4*)(bias + c0 + tx * 4);
#pragma unroll
      for (int i = 0; i < 4; ++i) {
        acc[i][0] = b4.x; acc[i][1] = b4.y; acc[i][2] = b4.z; acc[i][3] = b4.w;
      }
    } else {
#pragma unroll
      for (int i = 0; i < 4; ++i)
        for (int j = 0; j < 4; ++j) acc[i][j] = 0.f;
    }

    for (int kk = 0; kk < HID; kk += 64) {
      __syncthreads();
#pragma unroll
      for (int it = 0; it < 4; ++it) {
        int idx = it * 256 + tid;
        int r = idx >> 4;
        int q = idx & 15;
        *(float4*)&Ws[r][q * 4] = *(const float4*)(W + (size_t)(kk + r) * HID + c0 + q * 4);
      }
      __syncthreads();
#pragma unroll 2
      for (int k = 0; k < 64; k += 4) {
        float4 af[4];
#pragma unroll
        for (int i = 0; i < 4; ++i) af[i] = *(const float4*)&As[ty * 4 + i][kk + k];
#pragma unroll
        for (int k2 = 0; k2 < 4; ++k2) {
          float4 w4 = *(const float4*)&Ws[k + k2][tx * 4];
#pragma unroll
          for (int i = 0; i < 4; ++i) {
            float av = vget(af[i], k2);
            acc[i][0] = fmaf(av, w4.x, acc[i][0]);
            acc[i][1] = fmaf(av, w4.y, acc[i][1]);
            acc[i][2] = fmaf(av, w4.z, acc[i][2]);
            acc[i][3] = fmaf(av, w4.w, acc[i][3]);
          }
        }
      }
    }

    float* dstp = (t < 2) ? Z : OUT;
#pragma unroll
    for (int i = 0; i < 4; ++i) {
      int row = r0 + ty * 4 + i;
      if (row < N_NODES) {
        float4 v = make_float4(acc[i][0], acc[i][1], acc[i][2], acc[i][3]);
        *(float4*)(dstp + (size_t)row * HID + c0 + tx * 4) = v;
      }
    }
  }
}

// ---------------- Edge aggregation: OUT[i] = act(OUT[i] + sum_e Z[esrc[e]]) ----------------
__global__ __launch_bounds__(256) void agg_k(const float* __restrict__ Z,
                                             const int* __restrict__ row_ptr,
                                             const int* __restrict__ esrc,
                                             float* __restrict__ OUT, int do_relu) {
  int wave = threadIdx.x >> 6;
  int lane = threadIdx.x & 63;
  int node = blockIdx.x * 4 + wave;
  if (node >= N_NODES) return;
  int beg = row_ptr[node], end = row_ptr[node + 1];
  float2 acc = *(const float2*)&OUT[(size_t)node * HID + lane * 2];
  for (int e = beg; e < end; ++e) {
    int s = esrc[e];
    float2 z = *(const float2*)&Z[(size_t)s * HID + lane * 2];
    acc.x += z.x;
    acc.y += z.y;
  }
  if (do_relu) { acc.x = fmaxf(acc.x, 0.f); acc.y = fmaxf(acc.y, 0.f); }
  *(float2*)&OUT[(size_t)node * HID + lane * 2] = acc;
}

// ---------------- Mean pool (atomics) ----------------
__global__ __launch_bounds__(256) void pool_k(const float* __restrict__ H,
                                              const int* __restrict__ batch,
                                              float* __restrict__ pool, int* __restrict__ cnt) {
  int wave = threadIdx.x >> 6;
  int lane = threadIdx.x & 63;
  int node = blockIdx.x * 4 + wave;
  if (node >= N_NODES) return;
  int g = batch[node];
  float2 h = *(const float2*)&H[(size_t)node * HID + lane * 2];
  atomicAdd(&pool[(size_t)g * HID + lane * 2 + 0], h.x);
  atomicAdd(&pool[(size_t)g * HID + lane * 2 + 1], h.y);
  if (lane == 0) atomicAdd(&cnt[g], 1);
}

// ---------------- Final: sigmoid(pool/cnt @ Wlin + b) ----------------
__global__ __launch_bounds__(256) void final_k(const float* __restrict__ pool,
                                               const int* __restrict__ cnt,
                                               const float* __restrict__ Wlin,
                                               const float* __restrict__ blin,
                                               float* __restrict__ out) {
  int wave = threadIdx.x >> 6;
  int lane = threadIdx.x & 63;
  int g = blockIdx.x * 4 + wave;
  if (g >= NGRAPH) return;
  float2 p = *(const float2*)&pool[(size_t)g * HID + lane * 2];
  float v = p.x * Wlin[lane * 2 + 0] + p.y * Wlin[lane * 2 + 1];
#pragma unroll
  for (int off = 32; off; off >>= 1) v += __shfl_down(v, off, 64);
  if (lane == 0) {
    float c = (float)cnt[g];
    if (c < 1.f) c = 1.f;
    float logit = v / c + blin[0];
    out[g] = 1.f / (1.f + expf(-logit));
  }
}

extern "C" void kernel_launch(void* const* d_in, const int* in_sizes, int n_in,
                              void* d_out, int out_size, void* d_ws, size_t ws_size,
                              hipStream_t stream) {
  const float* x      = (const float*)d_in[0];
  const int*   ei     = (const int*)d_in[1];
  const int*   batch  = (const int*)d_in[2];
  const float* Wrel0  = (const float*)d_in[3];
  const float* brel0  = (const float*)d_in[4];
  const float* Wroot0 = (const float*)d_in[5];
  const float* Wrel1  = (const float*)d_in[6];
  const float* brel1  = (const float*)d_in[7];
  const float* Wroot1 = (const float*)d_in[8];
  const float* Wrel2  = (const float*)d_in[9];
  const float* brel2  = (const float*)d_in[10];
  const float* Wroot2 = (const float*)d_in[11];
  const float* Wlin   = (const float*)d_in[12];
  const float* blin   = (const float*)d_in[13];
  float* out = (float*)d_out;
  const int* srcp = ei;
  const int* dstp = ei + N_EDGES;

  char* ws = (char*)d_ws;
  size_t off = 0;
  auto alloc = [&](size_t b) { size_t o = off; off += (b + 255) & ~(size_t)255; return o; };
  float* Z    = (float*)(ws + alloc(sizeof(float) * N_NODES * HID));
  float* OUTA = (float*)(ws + alloc(sizeof(float) * N_NODES * HID));
  float* OUTB = (float*)(ws + alloc(sizeof(float) * N_NODES * HID));
  int* row_ptr  = (int*)(ws + alloc(sizeof(int) * (N_NODES + 1)));
  int* esrc     = (int*)(ws + alloc(sizeof(int) * N_EDGES));
  int* fill_off = (int*)(ws + alloc(sizeof(int) * N_NODES));
  int* bsum     = (int*)(ws + alloc(sizeof(int) * 256));
  int* boff     = (int*)(ws + alloc(sizeof(int) * 256));
  size_t zero_base = off;
  int* counts  = (int*)(ws + alloc(sizeof(int) * N_NODES));
  float* pool  = (float*)(ws + alloc(sizeof(float) * NGRAPH * HID));
  int* cnt     = (int*)(ws + alloc(sizeof(int) * NGRAPH));
  size_t zero_len = off - zero_base;

  hipMemsetAsync(ws + zero_base, 0, zero_len, stream);

  count_edges_k<<<(N_EDGES + 255) / 256, 256, 0, stream>>>(dstp, counts);
  partial_k<<<SCAN_NBLK, 256, 0, stream>>>(counts, bsum);
  scanb_k<<<1, 256, 0, stream>>>(bsum, boff, row_ptr);
  write_scan_k<<<SCAN_NBLK, 256, 0, stream>>>(counts, boff, row_ptr, fill_off);
  fill_edges_k<<<(N_EDGES + 255) / 256, 256, 0, stream>>>(srcp, dstp, fill_off, esrc);

  // Layer 0
  proj0_k<<<(N_NODES * HID + 255) / 256, 256, 0, stream>>>(x, Wrel0, brel0, Wroot0, Z, OUTA);
  agg_k<<<(N_NODES + 3) / 4, 256, 0, stream>>>(Z, row_ptr, esrc, OUTA, 1);
  // Layer 1
  gemm_k<<<(N_NODES + 63) / 64, 256, 0, stream>>>(OUTA, Wrel1, Wroot1, brel1, Z, OUTB);
  agg_k<<<(N_NODES + 3) / 4, 256, 0, stream>>>(Z, row_ptr, esrc, OUTB, 1);
  // Layer 2
  gemm_k<<<(N_NODES + 63) / 64, 256, 0, stream>>>(OUTB, Wrel2, Wroot2, brel2, Z, OUTA);
  agg_k<<<(N_NODES + 3) / 4, 256, 0, stream>>>(Z, row_ptr, esrc, OUTA, 0);

  pool_k<<<(N_NODES + 3) / 4, 256, 0, stream>>>(OUTA, batch, pool, cnt);
  final_k<<<(NGRAPH + 3) / 4, 256, 0, stream>>>(pool, cnt, Wlin, blin, out);
}

// Round 5
// 531.299 us; speedup vs baseline: 2.3268x; 1.1563x over previous
//
#include <hip/hip_runtime.h>
#include <hip/hip_bf16.h>
#include <math.h>

#define N_NODES 50000
#define N_EDGES 640000
#define IN_DIM 5
#define HID 128
#define NGRAPH 512
#define SCAN_NBLK ((N_NODES + 255) / 256)  // 196
#define POOL_CHUNK 64
#define POOL_NWAVE ((N_NODES + POOL_CHUNK - 1) / POOL_CHUNK)  // 782

__device__ __forceinline__ float vget(const float4& v, int k) {
  return k == 0 ? v.x : k == 1 ? v.y : k == 2 ? v.z : v.w;
}

// ---------------- CSR build ----------------
__global__ void count_edges_k(const int* __restrict__ dst, int* __restrict__ counts) {
  int e = blockIdx.x * blockDim.x + threadIdx.x;
  if (e < N_EDGES) atomicAdd(&counts[dst[e]], 1);
}

// 196 blocks x 256: per-block sum of counts
__global__ __launch_bounds__(256) void partial_k(const int* __restrict__ counts,
                                                 int* __restrict__ bsum) {
  int t = threadIdx.x;
  int i = blockIdx.x * 256 + t;
  int v = (i < N_NODES) ? counts[i] : 0;
#pragma unroll
  for (int off = 32; off; off >>= 1) v += __shfl_down(v, off, 64);
  __shared__ int ws[4];
  if ((t & 63) == 0) ws[t >> 6] = v;
  __syncthreads();
  if (t == 0) bsum[blockIdx.x] = ws[0] + ws[1] + ws[2] + ws[3];
}

// single small block: exclusive-scan the 196 block sums
__global__ __launch_bounds__(256) void scanb_k(const int* __restrict__ bsum,
                                               int* __restrict__ boff,
                                               int* __restrict__ row_ptr) {
  __shared__ int s[256];
  int t = threadIdx.x;
  int v = (t < SCAN_NBLK) ? bsum[t] : 0;
  s[t] = v;
  __syncthreads();
#pragma unroll
  for (int off = 1; off < 256; off <<= 1) {
    int u = (t >= off) ? s[t - off] : 0;
    __syncthreads();
    s[t] += u;
    __syncthreads();
  }
  if (t < SCAN_NBLK) boff[t] = s[t] - v;  // exclusive
  if (t == 255) row_ptr[N_NODES] = s[255];
}

// 196 blocks: local exclusive scan + block offset -> row_ptr / fill_off
__global__ __launch_bounds__(256) void write_scan_k(const int* __restrict__ counts,
                                                    const int* __restrict__ boff,
                                                    int* __restrict__ row_ptr,
                                                    int* __restrict__ fill_off) {
  __shared__ int s[256];
  int t = threadIdx.x;
  int i = blockIdx.x * 256 + t;
  int c = (i < N_NODES) ? counts[i] : 0;
  s[t] = c;
  __syncthreads();
#pragma unroll
  for (int off = 1; off < 256; off <<= 1) {
    int u = (t >= off) ? s[t - off] : 0;
    __syncthreads();
    s[t] += u;
    __syncthreads();
  }
  int excl = s[t] - c + boff[blockIdx.x];
  if (i < N_NODES) {
    row_ptr[i] = excl;
    fill_off[i] = excl;
  }
}

__global__ void fill_edges_k(const int* __restrict__ src, const int* __restrict__ dst,
                             int* __restrict__ fill_off, int* __restrict__ esrc) {
  int e = blockIdx.x * blockDim.x + threadIdx.x;
  if (e < N_EDGES) {
    int d = dst[e];
    int pos = atomicAdd(&fill_off[d], 1);
    esrc[pos] = src[e];
  }
}

// ---------------- Layer 0 projection (IN_DIM=5) ----------------
__global__ void proj0_k(const float* __restrict__ x, const float* __restrict__ Wrel,
                        const float* __restrict__ bias, const float* __restrict__ Wroot,
                        float* __restrict__ Z, float* __restrict__ OUT) {
  int idx = blockIdx.x * blockDim.x + threadIdx.x;  // node*128 + c
  if (idx >= N_NODES * HID) return;
  int i = idx >> 7, c = idx & 127;
  float xr[IN_DIM];
#pragma unroll
  for (int k = 0; k < IN_DIM; ++k) xr[k] = x[i * IN_DIM + k];
  float zr = 0.f, zo = bias[c];
#pragma unroll
  for (int k = 0; k < IN_DIM; ++k) {
    zr = fmaf(xr[k], Wrel[k * HID + c], zr);
    zo = fmaf(xr[k], Wroot[k * HID + c], zo);
  }
  Z[idx] = zr;
  OUT[idx] = zo;
}

// ---------------- GEMM for layers 1,2 ----------------
// One block = 64 A-rows. A staged to LDS once; 4 output tiles (rel/root x c0/c64).
// __launch_bounds__(256,4) caps VGPR<=128 (round-2: VGPR=256 caused ~700MB spill).
__global__ __launch_bounds__(256, 4) void gemm_k(const float* __restrict__ A,
                                                 const float* __restrict__ Wrel,
                                                 const float* __restrict__ Wroot,
                                                 const float* __restrict__ bias,
                                                 float* __restrict__ Z,
                                                 float* __restrict__ OUT) {
  __shared__ float As[64][132];
  __shared__ float Ws[64][68];
  int tid = threadIdx.x;
  int tx = tid & 15, ty = tid >> 4;
  int r0 = blockIdx.x * 64;

#pragma unroll
  for (int it = 0; it < 8; ++it) {
    int idx = it * 256 + tid;
    int row = idx >> 5;
    int q = idx & 31;
    int grow = r0 + row;
    float4 v = make_float4(0.f, 0.f, 0.f, 0.f);
    if (grow < N_NODES) v = *(const float4*)(A + (size_t)grow * HID + q * 4);
    *(float4*)&As[row][q * 4] = v;
  }

  for (int t = 0; t < 4; ++t) {
    const float* W = (t < 2) ? Wrel : Wroot;
    int c0 = (t & 1) * 64;
    float acc[4][4];
    if (t >= 2) {
      float4 b4 = *(const float4*)(bias + c0 + tx * 4);
#pragma unroll
      for (int i = 0; i < 4; ++i) {
        acc[i][0] = b4.x; acc[i][1] = b4.y; acc[i][2] = b4.z; acc[i][3] = b4.w;
      }
    } else {
#pragma unroll
      for (int i = 0; i < 4; ++i)
        for (int j = 0; j < 4; ++j) acc[i][j] = 0.f;
    }

    for (int kk = 0; kk < HID; kk += 64) {
      __syncthreads();
#pragma unroll
      for (int it = 0; it < 4; ++it) {
        int idx = it * 256 + tid;
        int r = idx >> 4;
        int q = idx & 15;
        *(float4*)&Ws[r][q * 4] = *(const float4*)(W + (size_t)(kk + r) * HID + c0 + q * 4);
      }
      __syncthreads();
#pragma unroll 2
      for (int k = 0; k < 64; k += 4) {
        float4 af[4];
#pragma unroll
        for (int i = 0; i < 4; ++i) af[i] = *(const float4*)&As[ty * 4 + i][kk + k];
#pragma unroll
        for (int k2 = 0; k2 < 4; ++k2) {
          float4 w4 = *(const float4*)&Ws[k + k2][tx * 4];
#pragma unroll
          for (int i = 0; i < 4; ++i) {
            float av = vget(af[i], k2);
            acc[i][0] = fmaf(av, w4.x, acc[i][0]);
            acc[i][1] = fmaf(av, w4.y, acc[i][1]);
            acc[i][2] = fmaf(av, w4.z, acc[i][2]);
            acc[i][3] = fmaf(av, w4.w, acc[i][3]);
          }
        }
      }
    }

    float* dstp = (t < 2) ? Z : OUT;
#pragma unroll
    for (int i = 0; i < 4; ++i) {
      int row = r0 + ty * 4 + i;
      if (row < N_NODES) {
        float4 v = make_float4(acc[i][0], acc[i][1], acc[i][2], acc[i][3]);
        *(float4*)(dstp + (size_t)row * HID + c0 + tx * 4) = v;
      }
    }
  }
}

// ---------------- Edge aggregation: OUT[i] = act(OUT[i] + sum_e Z[esrc[e]]) ----------------
__global__ __launch_bounds__(256) void agg_k(const float* __restrict__ Z,
                                             const int* __restrict__ row_ptr,
                                             const int* __restrict__ esrc,
                                             float* __restrict__ OUT, int do_relu) {
  int wave = threadIdx.x >> 6;
  int lane = threadIdx.x & 63;
  int node = blockIdx.x * 4 + wave;
  if (node >= N_NODES) return;
  int beg = row_ptr[node], end = row_ptr[node + 1];
  float2 acc = *(const float2*)&OUT[(size_t)node * HID + lane * 2];
  for (int e = beg; e < end; ++e) {
    int s = esrc[e];
    float2 z = *(const float2*)&Z[(size_t)s * HID + lane * 2];
    acc.x += z.x;
    acc.y += z.y;
  }
  if (do_relu) { acc.x = fmaxf(acc.x, 0.f); acc.y = fmaxf(acc.y, 0.f); }
  *(float2*)&OUT[(size_t)node * HID + lane * 2] = acc;
}

// ---------------- Mean pool: segmented reduction over SORTED batch ids ----------------
// batch is sorted => nodes of a graph are contiguous. Wave owns 64 nodes
// (lane <-> feature pair), accumulates in registers, atomics only at
// segment boundaries (~170k atomics vs 6.4M scatter atomics in round 4).
__global__ __launch_bounds__(256) void pool_seg_k(const float* __restrict__ H,
                                                  const int* __restrict__ batch,
                                                  float* __restrict__ pool,
                                                  int* __restrict__ cnt) {
  int wave = blockIdx.x * 4 + (threadIdx.x >> 6);
  int lane = threadIdx.x & 63;
  if (wave >= POOL_NWAVE) return;
  int n0 = wave * POOL_CHUNK;
  int n1 = n0 + POOL_CHUNK;
  if (n1 > N_NODES) n1 = N_NODES;
  int cur = batch[n0];
  float2 acc = make_float2(0.f, 0.f);
  int run = 0;
  for (int n = n0; n < n1; ++n) {
    int g = batch[n];  // wave-uniform
    if (g != cur) {
      atomicAdd(&pool[(size_t)cur * HID + lane * 2 + 0], acc.x);
      atomicAdd(&pool[(size_t)cur * HID + lane * 2 + 1], acc.y);
      if (lane == 0) atomicAdd(&cnt[cur], run);
      acc = make_float2(0.f, 0.f);
      run = 0;
      cur = g;
    }
    float2 h = *(const float2*)&H[(size_t)n * HID + lane * 2];
    acc.x += h.x;
    acc.y += h.y;
    run += 1;
  }
  atomicAdd(&pool[(size_t)cur * HID + lane * 2 + 0], acc.x);
  atomicAdd(&pool[(size_t)cur * HID + lane * 2 + 1], acc.y);
  if (lane == 0) atomicAdd(&cnt[cur], run);
}

// ---------------- Final: sigmoid(pool/cnt @ Wlin + b) ----------------
__global__ __launch_bounds__(256) void final_k(const float* __restrict__ pool,
                                               const int* __restrict__ cnt,
                                               const float* __restrict__ Wlin,
                                               const float* __restrict__ blin,
                                               float* __restrict__ out) {
  int wave = threadIdx.x >> 6;
  int lane = threadIdx.x & 63;
  int g = blockIdx.x * 4 + wave;
  if (g >= NGRAPH) return;
  float2 p = *(const float2*)&pool[(size_t)g * HID + lane * 2];
  float v = p.x * Wlin[lane * 2 + 0] + p.y * Wlin[lane * 2 + 1];
#pragma unroll
  for (int off = 32; off; off >>= 1) v += __shfl_down(v, off, 64);
  if (lane == 0) {
    float c = (float)cnt[g];
    if (c < 1.f) c = 1.f;
    float logit = v / c + blin[0];
    out[g] = 1.f / (1.f + expf(-logit));
  }
}

extern "C" void kernel_launch(void* const* d_in, const int* in_sizes, int n_in,
                              void* d_out, int out_size, void* d_ws, size_t ws_size,
                              hipStream_t stream) {
  const float* x      = (const float*)d_in[0];
  const int*   ei     = (const int*)d_in[1];
  const int*   batch  = (const int*)d_in[2];
  const float* Wrel0  = (const float*)d_in[3];
  const float* brel0  = (const float*)d_in[4];
  const float* Wroot0 = (const float*)d_in[5];
  const float* Wrel1  = (const float*)d_in[6];
  const float* brel1  = (const float*)d_in[7];
  const float* Wroot1 = (const float*)d_in[8];
  const float* Wrel2  = (const float*)d_in[9];
  const float* brel2  = (const float*)d_in[10];
  const float* Wroot2 = (const float*)d_in[11];
  const float* Wlin   = (const float*)d_in[12];
  const float* blin   = (const float*)d_in[13];
  float* out = (float*)d_out;
  const int* srcp = ei;
  const int* dstp = ei + N_EDGES;

  char* ws = (char*)d_ws;
  size_t off = 0;
  auto alloc = [&](size_t b) { size_t o = off; off += (b + 255) & ~(size_t)255; return o; };
  float* Z    = (float*)(ws + alloc(sizeof(float) * N_NODES * HID));
  float* OUTA = (float*)(ws + alloc(sizeof(float) * N_NODES * HID));
  float* OUTB = (float*)(ws + alloc(sizeof(float) * N_NODES * HID));
  int* row_ptr  = (int*)(ws + alloc(sizeof(int) * (N_NODES + 1)));
  int* esrc     = (int*)(ws + alloc(sizeof(int) * N_EDGES));
  int* fill_off = (int*)(ws + alloc(sizeof(int) * N_NODES));
  int* bsum     = (int*)(ws + alloc(sizeof(int) * 256));
  int* boff     = (int*)(ws + alloc(sizeof(int) * 256));
  size_t zero_base = off;
  int* counts  = (int*)(ws + alloc(sizeof(int) * N_NODES));
  float* pool  = (float*)(ws + alloc(sizeof(float) * NGRAPH * HID));
  int* cnt     = (int*)(ws + alloc(sizeof(int) * NGRAPH));
  size_t zero_len = off - zero_base;

  hipMemsetAsync(ws + zero_base, 0, zero_len, stream);

  count_edges_k<<<(N_EDGES + 255) / 256, 256, 0, stream>>>(dstp, counts);
  partial_k<<<SCAN_NBLK, 256, 0, stream>>>(counts, bsum);
  scanb_k<<<1, 256, 0, stream>>>(bsum, boff, row_ptr);
  write_scan_k<<<SCAN_NBLK, 256, 0, stream>>>(counts, boff, row_ptr, fill_off);
  fill_edges_k<<<(N_EDGES + 255) / 256, 256, 0, stream>>>(srcp, dstp, fill_off, esrc);

  // Layer 0
  proj0_k<<<(N_NODES * HID + 255) / 256, 256, 0, stream>>>(x, Wrel0, brel0, Wroot0, Z, OUTA);
  agg_k<<<(N_NODES + 3) / 4, 256, 0, stream>>>(Z, row_ptr, esrc, OUTA, 1);
  // Layer 1
  gemm_k<<<(N_NODES + 63) / 64, 256, 0, stream>>>(OUTA, Wrel1, Wroot1, brel1, Z, OUTB);
  agg_k<<<(N_NODES + 3) / 4, 256, 0, stream>>>(Z, row_ptr, esrc, OUTB, 1);
  // Layer 2
  gemm_k<<<(N_NODES + 63) / 64, 256, 0, stream>>>(OUTB, Wrel2, Wroot2, brel2, Z, OUTA);
  agg_k<<<(N_NODES + 3) / 4, 256, 0, stream>>>(Z, row_ptr, esrc, OUTA, 0);

  pool_seg_k<<<(POOL_NWAVE + 3) / 4, 256, 0, stream>>>(OUTA, batch, pool, cnt);
  final_k<<<(NGRAPH + 3) / 4, 256, 0, stream>>>(pool, cnt, Wlin, blin, out);
}

// Round 6
// 446.841 us; speedup vs baseline: 2.7666x; 1.1890x over previous
//
#include <hip/hip_runtime.h>
#include <hip/hip_bf16.h>
#include <math.h>

#define N_NODES 50000
#define N_EDGES 640000
#define IN_DIM 5
#define HID 128
#define NGRAPH 512
#define SCAN_NBLK ((N_NODES + 255) / 256)  // 196
#define POOL_CHUNK 64
#define POOL_NWAVE ((N_NODES + POOL_CHUNK - 1) / POOL_CHUNK)  // 782

typedef unsigned short u16;

__device__ __forceinline__ float vget(const float4& v, int k) {
  return k == 0 ? v.x : k == 1 ? v.y : k == 2 ? v.z : v.w;
}
__device__ __forceinline__ float bf2f(u16 u) {
  union { unsigned int i; float f; } v; v.i = ((unsigned int)u) << 16; return v.f;
}
__device__ __forceinline__ u16 f2bf(float f) {
  return __bfloat16_as_ushort(__float2bfloat16(f));
}

// ---------------- CSR build ----------------
__global__ void count_edges_k(const int* __restrict__ dst, int* __restrict__ counts) {
  int e = blockIdx.x * blockDim.x + threadIdx.x;
  if (e < N_EDGES) atomicAdd(&counts[dst[e]], 1);
}

__global__ __launch_bounds__(256) void partial_k(const int* __restrict__ counts,
                                                 int* __restrict__ bsum) {
  int t = threadIdx.x;
  int i = blockIdx.x * 256 + t;
  int v = (i < N_NODES) ? counts[i] : 0;
#pragma unroll
  for (int off = 32; off; off >>= 1) v += __shfl_down(v, off, 64);
  __shared__ int ws[4];
  if ((t & 63) == 0) ws[t >> 6] = v;
  __syncthreads();
  if (t == 0) bsum[blockIdx.x] = ws[0] + ws[1] + ws[2] + ws[3];
}

__global__ __launch_bounds__(256) void scanb_k(const int* __restrict__ bsum,
                                               int* __restrict__ boff,
                                               int* __restrict__ row_ptr) {
  __shared__ int s[256];
  int t = threadIdx.x;
  int v = (t < SCAN_NBLK) ? bsum[t] : 0;
  s[t] = v;
  __syncthreads();
#pragma unroll
  for (int off = 1; off < 256; off <<= 1) {
    int u = (t >= off) ? s[t - off] : 0;
    __syncthreads();
    s[t] += u;
    __syncthreads();
  }
  if (t < SCAN_NBLK) boff[t] = s[t] - v;
  if (t == 255) row_ptr[N_NODES] = s[255];
}

__global__ __launch_bounds__(256) void write_scan_k(const int* __restrict__ counts,
                                                    const int* __restrict__ boff,
                                                    int* __restrict__ row_ptr,
                                                    int* __restrict__ fill_off) {
  __shared__ int s[256];
  int t = threadIdx.x;
  int i = blockIdx.x * 256 + t;
  int c = (i < N_NODES) ? counts[i] : 0;
  s[t] = c;
  __syncthreads();
#pragma unroll
  for (int off = 1; off < 256; off <<= 1) {
    int u = (t >= off) ? s[t - off] : 0;
    __syncthreads();
    s[t] += u;
    __syncthreads();
  }
  int excl = s[t] - c + boff[blockIdx.x];
  if (i < N_NODES) {
    row_ptr[i] = excl;
    fill_off[i] = excl;
  }
}

__global__ void fill_edges_k(const int* __restrict__ src, const int* __restrict__ dst,
                             int* __restrict__ fill_off, int* __restrict__ esrc) {
  int e = blockIdx.x * blockDim.x + threadIdx.x;
  if (e < N_EDGES) {
    int d = dst[e];
    int pos = atomicAdd(&fill_off[d], 1);
    esrc[pos] = src[e];
  }
}

// ---------------- Layer 0 projection (IN_DIM=5); Z emitted bf16 ----------------
__global__ void proj0_k(const float* __restrict__ x, const float* __restrict__ Wrel,
                        const float* __restrict__ bias, const float* __restrict__ Wroot,
                        u16* __restrict__ Z, float* __restrict__ OUT) {
  int idx = blockIdx.x * blockDim.x + threadIdx.x;  // node*128 + c
  if (idx >= N_NODES * HID) return;
  int i = idx >> 7, c = idx & 127;
  float xr[IN_DIM];
#pragma unroll
  for (int k = 0; k < IN_DIM; ++k) xr[k] = x[i * IN_DIM + k];
  float zr = 0.f, zo = bias[c];
#pragma unroll
  for (int k = 0; k < IN_DIM; ++k) {
    zr = fmaf(xr[k], Wrel[k * HID + c], zr);
    zo = fmaf(xr[k], Wroot[k * HID + c], zo);
  }
  Z[idx] = f2bf(zr);
  OUT[idx] = zo;
}

// ---------------- GEMM for layers 1,2 (Z output bf16, OUT f32) ----------------
__global__ __launch_bounds__(256, 4) void gemm_k(const float* __restrict__ A,
                                                 const float* __restrict__ Wrel,
                                                 const float* __restrict__ Wroot,
                                                 const float* __restrict__ bias,
                                                 u16* __restrict__ Z,
                                                 float* __restrict__ OUT) {
  __shared__ float As[64][132];
  __shared__ float Ws[64][68];
  int tid = threadIdx.x;
  int tx = tid & 15, ty = tid >> 4;
  int r0 = blockIdx.x * 64;

#pragma unroll
  for (int it = 0; it < 8; ++it) {
    int idx = it * 256 + tid;
    int row = idx >> 5;
    int q = idx & 31;
    int grow = r0 + row;
    float4 v = make_float4(0.f, 0.f, 0.f, 0.f);
    if (grow < N_NODES) v = *(const float4*)(A + (size_t)grow * HID + q * 4);
    *(float4*)&As[row][q * 4] = v;
  }

  for (int t = 0; t < 4; ++t) {
    const float* W = (t < 2) ? Wrel : Wroot;
    int c0 = (t & 1) * 64;
    float acc[4][4];
    if (t >= 2) {
      float4 b4 = *(const float4*)(bias + c0 + tx * 4);
#pragma unroll
      for (int i = 0; i < 4; ++i) {
        acc[i][0] = b4.x; acc[i][1] = b4.y; acc[i][2] = b4.z; acc[i][3] = b4.w;
      }
    } else {
#pragma unroll
      for (int i = 0; i < 4; ++i)
        for (int j = 0; j < 4; ++j) acc[i][j] = 0.f;
    }

    for (int kk = 0; kk < HID; kk += 64) {
      __syncthreads();
#pragma unroll
      for (int it = 0; it < 4; ++it) {
        int idx = it * 256 + tid;
        int r = idx >> 4;
        int q = idx & 15;
        *(float4*)&Ws[r][q * 4] = *(const float4*)(W + (size_t)(kk + r) * HID + c0 + q * 4);
      }
      __syncthreads();
#pragma unroll 2
      for (int k = 0; k < 64; k += 4) {
        float4 af[4];
#pragma unroll
        for (int i = 0; i < 4; ++i) af[i] = *(const float4*)&As[ty * 4 + i][kk + k];
#pragma unroll
        for (int k2 = 0; k2 < 4; ++k2) {
          float4 w4 = *(const float4*)&Ws[k + k2][tx * 4];
#pragma unroll
          for (int i = 0; i < 4; ++i) {
            float av = vget(af[i], k2);
            acc[i][0] = fmaf(av, w4.x, acc[i][0]);
            acc[i][1] = fmaf(av, w4.y, acc[i][1]);
            acc[i][2] = fmaf(av, w4.z, acc[i][2]);
            acc[i][3] = fmaf(av, w4.w, acc[i][3]);
          }
        }
      }
    }

#pragma unroll
    for (int i = 0; i < 4; ++i) {
      int row = r0 + ty * 4 + i;
      if (row < N_NODES) {
        if (t < 2) {
          ushort4 zb;
          zb.x = f2bf(acc[i][0]); zb.y = f2bf(acc[i][1]);
          zb.z = f2bf(acc[i][2]); zb.w = f2bf(acc[i][3]);
          *(ushort4*)(Z + (size_t)row * HID + c0 + tx * 4) = zb;
        } else {
          float4 v = make_float4(acc[i][0], acc[i][1], acc[i][2], acc[i][3]);
          *(float4*)(OUT + (size_t)row * HID + c0 + tx * 4) = v;
        }
      }
    }
  }
}

// ---------------- Edge aggregation (bf16 Z): OUT[i] = act(OUT[i] + sum_e Z[esrc[e]]) ----
// Wave per node, 2 edges/iter: lanes 0-31 edge e, lanes 32-63 edge e+1,
// each lane loads ushort4 (4 features). f32 accumulate; halves combined
// via shfl_xor(32); lanes 0-31 do the f32 OUT rmw.
__global__ __launch_bounds__(256) void agg_k(const u16* __restrict__ Z,
                                             const int* __restrict__ row_ptr,
                                             const int* __restrict__ esrc,
                                             float* __restrict__ OUT, int do_relu) {
  int wave = threadIdx.x >> 6;
  int lane = threadIdx.x & 63;
  int node = blockIdx.x * 4 + wave;
  if (node >= N_NODES) return;
  int half = lane >> 5;        // 0 or 1
  int fq = (lane & 31) * 4;    // feature quad base
  int beg = row_ptr[node], end = row_ptr[node + 1];
  float4 acc = make_float4(0.f, 0.f, 0.f, 0.f);
  for (int e = beg + half; e < end; e += 2) {
    int s = esrc[e];
    ushort4 z4 = *(const ushort4*)(Z + (size_t)s * HID + fq);
    acc.x += bf2f(z4.x);
    acc.y += bf2f(z4.y);
    acc.z += bf2f(z4.z);
    acc.w += bf2f(z4.w);
  }
  acc.x += __shfl_xor(acc.x, 32, 64);
  acc.y += __shfl_xor(acc.y, 32, 64);
  acc.z += __shfl_xor(acc.z, 32, 64);
  acc.w += __shfl_xor(acc.w, 32, 64);
  if (half == 0) {
    float4 o = *(const float4*)&OUT[(size_t)node * HID + fq];
    o.x += acc.x; o.y += acc.y; o.z += acc.z; o.w += acc.w;
    if (do_relu) {
      o.x = fmaxf(o.x, 0.f); o.y = fmaxf(o.y, 0.f);
      o.z = fmaxf(o.z, 0.f); o.w = fmaxf(o.w, 0.f);
    }
    *(float4*)&OUT[(size_t)node * HID + fq] = o;
  }
}

// ---------------- Mean pool: segmented reduction over SORTED batch ids ----------------
__global__ __launch_bounds__(256) void pool_seg_k(const float* __restrict__ H,
                                                  const int* __restrict__ batch,
                                                  float* __restrict__ pool,
                                                  int* __restrict__ cnt) {
  int wave = blockIdx.x * 4 + (threadIdx.x >> 6);
  int lane = threadIdx.x & 63;
  if (wave >= POOL_NWAVE) return;
  int n0 = wave * POOL_CHUNK;
  int n1 = n0 + POOL_CHUNK;
  if (n1 > N_NODES) n1 = N_NODES;
  int cur = batch[n0];
  float2 acc = make_float2(0.f, 0.f);
  int run = 0;
  for (int n = n0; n < n1; ++n) {
    int g = batch[n];  // wave-uniform
    if (g != cur) {
      atomicAdd(&pool[(size_t)cur * HID + lane * 2 + 0], acc.x);
      atomicAdd(&pool[(size_t)cur * HID + lane * 2 + 1], acc.y);
      if (lane == 0) atomicAdd(&cnt[cur], run);
      acc = make_float2(0.f, 0.f);
      run = 0;
      cur = g;
    }
    float2 h = *(const float2*)&H[(size_t)n * HID + lane * 2];
    acc.x += h.x;
    acc.y += h.y;
    run += 1;
  }
  atomicAdd(&pool[(size_t)cur * HID + lane * 2 + 0], acc.x);
  atomicAdd(&pool[(size_t)cur * HID + lane * 2 + 1], acc.y);
  if (lane == 0) atomicAdd(&cnt[cur], run);
}

// ---------------- Final: sigmoid(pool/cnt @ Wlin + b) ----------------
__global__ __launch_bounds__(256) void final_k(const float* __restrict__ pool,
                                               const int* __restrict__ cnt,
                                               const float* __restrict__ Wlin,
                                               const float* __restrict__ blin,
                                               float* __restrict__ out) {
  int wave = threadIdx.x >> 6;
  int lane = threadIdx.x & 63;
  int g = blockIdx.x * 4 + wave;
  if (g >= NGRAPH) return;
  float2 p = *(const float2*)&pool[(size_t)g * HID + lane * 2];
  float v = p.x * Wlin[lane * 2 + 0] + p.y * Wlin[lane * 2 + 1];
#pragma unroll
  for (int off = 32; off; off >>= 1) v += __shfl_down(v, off, 64);
  if (lane == 0) {
    float c = (float)cnt[g];
    if (c < 1.f) c = 1.f;
    float logit = v / c + blin[0];
    out[g] = 1.f / (1.f + expf(-logit));
  }
}

extern "C" void kernel_launch(void* const* d_in, const int* in_sizes, int n_in,
                              void* d_out, int out_size, void* d_ws, size_t ws_size,
                              hipStream_t stream) {
  const float* x      = (const float*)d_in[0];
  const int*   ei     = (const int*)d_in[1];
  const int*   batch  = (const int*)d_in[2];
  const float* Wrel0  = (const float*)d_in[3];
  const float* brel0  = (const float*)d_in[4];
  const float* Wroot0 = (const float*)d_in[5];
  const float* Wrel1  = (const float*)d_in[6];
  const float* brel1  = (const float*)d_in[7];
  const float* Wroot1 = (const float*)d_in[8];
  const float* Wrel2  = (const float*)d_in[9];
  const float* brel2  = (const float*)d_in[10];
  const float* Wroot2 = (const float*)d_in[11];
  const float* Wlin   = (const float*)d_in[12];
  const float* blin   = (const float*)d_in[13];
  float* out = (float*)d_out;
  const int* srcp = ei;
  const int* dstp = ei + N_EDGES;

  char* ws = (char*)d_ws;
  size_t off = 0;
  auto alloc = [&](size_t b) { size_t o = off; off += (b + 255) & ~(size_t)255; return o; };
  u16*  Z     = (u16*)(ws + alloc(sizeof(u16) * N_NODES * HID));
  float* OUTA = (float*)(ws + alloc(sizeof(float) * N_NODES * HID));
  float* OUTB = (float*)(ws + alloc(sizeof(float) * N_NODES * HID));
  int* row_ptr  = (int*)(ws + alloc(sizeof(int) * (N_NODES + 1)));
  int* esrc     = (int*)(ws + alloc(sizeof(int) * N_EDGES));
  int* fill_off = (int*)(ws + alloc(sizeof(int) * N_NODES));
  int* bsum     = (int*)(ws + alloc(sizeof(int) * 256));
  int* boff     = (int*)(ws + alloc(sizeof(int) * 256));
  size_t zero_base = off;
  int* counts  = (int*)(ws + alloc(sizeof(int) * N_NODES));
  float* pool  = (float*)(ws + alloc(sizeof(float) * NGRAPH * HID));
  int* cnt     = (int*)(ws + alloc(sizeof(int) * NGRAPH));
  size_t zero_len = off - zero_base;

  hipMemsetAsync(ws + zero_base, 0, zero_len, stream);

  count_edges_k<<<(N_EDGES + 255) / 256, 256, 0, stream>>>(dstp, counts);
  partial_k<<<SCAN_NBLK, 256, 0, stream>>>(counts, bsum);
  scanb_k<<<1, 256, 0, stream>>>(bsum, boff, row_ptr);
  write_scan_k<<<SCAN_NBLK, 256, 0, stream>>>(counts, boff, row_ptr, fill_off);
  fill_edges_k<<<(N_EDGES + 255) / 256, 256, 0, stream>>>(srcp, dstp, fill_off, esrc);

  // Layer 0
  proj0_k<<<(N_NODES * HID + 255) / 256, 256, 0, stream>>>(x, Wrel0, brel0, Wroot0, Z, OUTA);
  agg_k<<<(N_NODES + 3) / 4, 256, 0, stream>>>(Z, row_ptr, esrc, OUTA, 1);
  // Layer 1
  gemm_k<<<(N_NODES + 63) / 64, 256, 0, stream>>>(OUTA, Wrel1, Wroot1, brel1, Z, OUTB);
  agg_k<<<(N_NODES + 3) / 4, 256, 0, stream>>>(Z, row_ptr, esrc, OUTB, 1);
  // Layer 2
  gemm_k<<<(N_NODES + 63) / 64, 256, 0, stream>>>(OUTB, Wrel2, Wroot2, brel2, Z, OUTA);
  agg_k<<<(N_NODES + 3) / 4, 256, 0, stream>>>(Z, row_ptr, esrc, OUTA, 0);

  pool_seg_k<<<(POOL_NWAVE + 3) / 4, 256, 0, stream>>>(OUTA, batch, pool, cnt);
  final_k<<<(NGRAPH + 3) / 4, 256, 0, stream>>>(pool, cnt, Wlin, blin, out);
}

// Round 7
// 381.602 us; speedup vs baseline: 3.2396x; 1.1710x over previous
//
#include <hip/hip_runtime.h>
#include <hip/hip_bf16.h>
#include <math.h>

#define N_NODES 50000
#define N_EDGES 640000
#define IN_DIM 5
#define HID 128
#define NGRAPH 512
#define SCAN_NBLK ((N_NODES + 255) / 256)  // 196
#define POOL_CHUNK 64
#define POOL_NWAVE ((N_NODES + POOL_CHUNK - 1) / POOL_CHUNK)  // 782
#define GEMM_NBLK ((N_NODES + 63) / 64)    // 782

typedef unsigned short u16;
typedef __attribute__((ext_vector_type(8))) short bf16x8;
typedef __attribute__((ext_vector_type(4))) float f32x4;

__device__ __forceinline__ float bf2f(u16 u) {
  union { unsigned int i; float f; } v; v.i = ((unsigned int)u) << 16; return v.f;
}
__device__ __forceinline__ u16 f2bf(float f) {
  return __bfloat16_as_ushort(__float2bfloat16(f));
}

// ---------------- CSR build ----------------
__global__ void count_edges_k(const int* __restrict__ dst, int* __restrict__ counts) {
  int e = blockIdx.x * blockDim.x + threadIdx.x;
  if (e < N_EDGES) atomicAdd(&counts[dst[e]], 1);
}

__global__ __launch_bounds__(256) void partial_k(const int* __restrict__ counts,
                                                 int* __restrict__ bsum) {
  int t = threadIdx.x;
  int i = blockIdx.x * 256 + t;
  int v = (i < N_NODES) ? counts[i] : 0;
#pragma unroll
  for (int off = 32; off; off >>= 1) v += __shfl_down(v, off, 64);
  __shared__ int ws[4];
  if ((t & 63) == 0) ws[t >> 6] = v;
  __syncthreads();
  if (t == 0) bsum[blockIdx.x] = ws[0] + ws[1] + ws[2] + ws[3];
}

__global__ __launch_bounds__(256) void scanb_k(const int* __restrict__ bsum,
                                               int* __restrict__ boff,
                                               int* __restrict__ row_ptr) {
  __shared__ int s[256];
  int t = threadIdx.x;
  int v = (t < SCAN_NBLK) ? bsum[t] : 0;
  s[t] = v;
  __syncthreads();
#pragma unroll
  for (int off = 1; off < 256; off <<= 1) {
    int u = (t >= off) ? s[t - off] : 0;
    __syncthreads();
    s[t] += u;
    __syncthreads();
  }
  if (t < SCAN_NBLK) boff[t] = s[t] - v;
  if (t == 255) row_ptr[N_NODES] = s[255];
}

__global__ __launch_bounds__(256) void write_scan_k(const int* __restrict__ counts,
                                                    const int* __restrict__ boff,
                                                    int* __restrict__ row_ptr,
                                                    int* __restrict__ fill_off) {
  __shared__ int s[256];
  int t = threadIdx.x;
  int i = blockIdx.x * 256 + t;
  int c = (i < N_NODES) ? counts[i] : 0;
  s[t] = c;
  __syncthreads();
#pragma unroll
  for (int off = 1; off < 256; off <<= 1) {
    int u = (t >= off) ? s[t - off] : 0;
    __syncthreads();
    s[t] += u;
    __syncthreads();
  }
  int excl = s[t] - c + boff[blockIdx.x];
  if (i < N_NODES) {
    row_ptr[i] = excl;
    fill_off[i] = excl;
  }
}

__global__ void fill_edges_k(const int* __restrict__ src, const int* __restrict__ dst,
                             int* __restrict__ fill_off, int* __restrict__ esrc) {
  int e = blockIdx.x * blockDim.x + threadIdx.x;
  if (e < N_EDGES) {
    int d = dst[e];
    int pos = atomicAdd(&fill_off[d], 1);
    esrc[pos] = src[e];
  }
}

// ---------------- Weight prep: W f32 [k][n] -> WT bf16 [n][k] (B-fragment layout) ----
__global__ __launch_bounds__(256) void prep_w_k(const float* __restrict__ W,
                                                u16* __restrict__ WT) {
  int idx = blockIdx.x * 256 + threadIdx.x;  // k*128 + n (coalesced read)
  if (idx >= HID * HID) return;
  int k = idx >> 7, n = idx & 127;
  WT[n * HID + k] = f2bf(W[idx]);
}

// ---------------- Layer 0 projection (IN_DIM=5); Z and root-init bf16 ----------------
__global__ void proj0_k(const float* __restrict__ x, const float* __restrict__ Wrel,
                        const float* __restrict__ bias, const float* __restrict__ Wroot,
                        u16* __restrict__ Z, u16* __restrict__ OUT) {
  int idx = blockIdx.x * blockDim.x + threadIdx.x;  // node*128 + c
  if (idx >= N_NODES * HID) return;
  int i = idx >> 7, c = idx & 127;
  float xr[IN_DIM];
#pragma unroll
  for (int k = 0; k < IN_DIM; ++k) xr[k] = x[i * IN_DIM + k];
  float zr = 0.f, zo = bias[c];
#pragma unroll
  for (int k = 0; k < IN_DIM; ++k) {
    zr = fmaf(xr[k], Wrel[k * HID + c], zr);
    zo = fmaf(xr[k], Wroot[k * HID + c], zo);
  }
  Z[idx] = f2bf(zr);
  OUT[idx] = f2bf(zo);
}

// ---------------- MFMA GEMM for layers 1,2 ----------------
// A bf16 [N,128]. 64 rows/block, 4 waves: wave w -> {rel,root} x {n0=0,64}.
// Per wave: 4 k-steps x (4 m-tiles x 4 n-tiles) mfma_f32_16x16x32_bf16.
// WT is bf16 [n][k]: lane's B-frag (n=n0+nt*16+lane&15, k contiguous) = one 16B load.
// Epilogue: rel -> Z bf16; root -> +bias, R bf16 (layer1) or f32 (layer2).
__global__ __launch_bounds__(256, 3) void gemm_mfma_k(const u16* __restrict__ A,
                                                      const u16* __restrict__ WrelT,
                                                      const u16* __restrict__ WrootT,
                                                      const float* __restrict__ bias,
                                                      u16* __restrict__ Z,
                                                      void* __restrict__ R,
                                                      int r_is_f32) {
  __shared__ u16 As[64][136];  // pad +8 bf16 -> 2-way max bank aliasing (free)
  int tid = threadIdx.x;
  int wv = tid >> 6, lane = tid & 63;
  int m = lane & 15, quad = lane >> 4;
  int r0 = blockIdx.x * 64;

  // Stage A tile: 64 rows x 128 bf16 = 1024 x 16B
#pragma unroll
  for (int it = 0; it < 4; ++it) {
    int idx = it * 256 + tid;
    int row = idx >> 4, q = idx & 15;
    int grow = r0 + row;
    float4 v = make_float4(0.f, 0.f, 0.f, 0.f);
    if (grow < N_NODES) v = *(const float4*)(A + (size_t)grow * HID + q * 8);
    *(float4*)&As[row][q * 8] = v;
  }
  __syncthreads();

  const u16* WT = (wv < 2) ? WrelT : WrootT;
  int n0 = (wv & 1) * 64;

  f32x4 acc[4][4];
#pragma unroll
  for (int mt = 0; mt < 4; ++mt)
#pragma unroll
    for (int nt = 0; nt < 4; ++nt) acc[mt][nt] = (f32x4){0.f, 0.f, 0.f, 0.f};

#pragma unroll
  for (int ks = 0; ks < 4; ++ks) {
    int kb = ks * 32;
    bf16x8 af[4], bf[4];
#pragma unroll
    for (int mt = 0; mt < 4; ++mt)
      af[mt] = *(const bf16x8*)&As[mt * 16 + m][kb + quad * 8];
#pragma unroll
    for (int nt = 0; nt < 4; ++nt)
      bf[nt] = *(const bf16x8*)(WT + (size_t)(n0 + nt * 16 + m) * HID + kb + quad * 8);
#pragma unroll
    for (int mt = 0; mt < 4; ++mt)
#pragma unroll
      for (int nt = 0; nt < 4; ++nt)
        acc[mt][nt] = __builtin_amdgcn_mfma_f32_16x16x32_bf16(af[mt], bf[nt], acc[mt][nt], 0, 0, 0);
  }

  // Epilogue. C/D layout: col = lane&15, row = quad*4 + reg.
  if (wv < 2) {
#pragma unroll
    for (int mt = 0; mt < 4; ++mt) {
#pragma unroll
      for (int nt = 0; nt < 4; ++nt) {
        int col = n0 + nt * 16 + m;
#pragma unroll
        for (int r = 0; r < 4; ++r) {
          int row = r0 + mt * 16 + quad * 4 + r;
          if (row < N_NODES) Z[(size_t)row * HID + col] = f2bf(acc[mt][nt][r]);
        }
      }
    }
  } else {
    float bl[4];
#pragma unroll
    for (int nt = 0; nt < 4; ++nt) bl[nt] = bias[n0 + nt * 16 + m];
#pragma unroll
    for (int mt = 0; mt < 4; ++mt) {
#pragma unroll
      for (int nt = 0; nt < 4; ++nt) {
        int col = n0 + nt * 16 + m;
#pragma unroll
        for (int r = 0; r < 4; ++r) {
          int row = r0 + mt * 16 + quad * 4 + r;
          if (row < N_NODES) {
            float v = acc[mt][nt][r] + bl[nt];
            if (r_is_f32) ((float*)R)[(size_t)row * HID + col] = v;
            else          ((u16*)R)[(size_t)row * HID + col] = f2bf(v);
          }
        }
      }
    }
  }
}

// ---------------- Edge aggregation (bf16 Z): OUT[i] = act(OUT[i] + sum_e Z[esrc[e]]) ----
// mode 0: OUT bf16 rmw + ReLU (layers 0,1). mode 1: OUT f32 rmw, no act (layer 2).
__global__ __launch_bounds__(256) void agg_k(const u16* __restrict__ Z,
                                             const int* __restrict__ row_ptr,
                                             const int* __restrict__ esrc,
                                             void* __restrict__ OUT, int mode) {
  int wave = threadIdx.x >> 6;
  int lane = threadIdx.x & 63;
  int node = blockIdx.x * 4 + wave;
  if (node >= N_NODES) return;
  int half = lane >> 5;
  int fq = (lane & 31) * 4;
  int beg = row_ptr[node], end = row_ptr[node + 1];
  float4 acc = make_float4(0.f, 0.f, 0.f, 0.f);
  for (int e = beg + half; e < end; e += 2) {
    int s = esrc[e];
    ushort4 z4 = *(const ushort4*)(Z + (size_t)s * HID + fq);
    acc.x += bf2f(z4.x);
    acc.y += bf2f(z4.y);
    acc.z += bf2f(z4.z);
    acc.w += bf2f(z4.w);
  }
  acc.x += __shfl_xor(acc.x, 32, 64);
  acc.y += __shfl_xor(acc.y, 32, 64);
  acc.z += __shfl_xor(acc.z, 32, 64);
  acc.w += __shfl_xor(acc.w, 32, 64);
  if (half == 0) {
    if (mode == 0) {
      u16* o = (u16*)OUT + (size_t)node * HID + fq;
      ushort4 o4 = *(const ushort4*)o;
      float a = bf2f(o4.x) + acc.x, b = bf2f(o4.y) + acc.y;
      float c = bf2f(o4.z) + acc.z, d = bf2f(o4.w) + acc.w;
      ushort4 w4;
      w4.x = f2bf(fmaxf(a, 0.f)); w4.y = f2bf(fmaxf(b, 0.f));
      w4.z = f2bf(fmaxf(c, 0.f)); w4.w = f2bf(fmaxf(d, 0.f));
      *(ushort4*)o = w4;
    } else {
      float* o = (float*)OUT + (size_t)node * HID + fq;
      float4 o4 = *(const float4*)o;
      o4.x += acc.x; o4.y += acc.y; o4.z += acc.z; o4.w += acc.w;
      *(float4*)o = o4;
    }
  }
}

// ---------------- Mean pool: segmented reduction over SORTED batch ids ----------------
__global__ __launch_bounds__(256) void pool_seg_k(const float* __restrict__ H,
                                                  const int* __restrict__ batch,
                                                  float* __restrict__ pool,
                                                  int* __restrict__ cnt) {
  int wave = blockIdx.x * 4 + (threadIdx.x >> 6);
  int lane = threadIdx.x & 63;
  if (wave >= POOL_NWAVE) return;
  int n0 = wave * POOL_CHUNK;
  int n1 = n0 + POOL_CHUNK;
  if (n1 > N_NODES) n1 = N_NODES;
  int cur = batch[n0];
  float2 acc = make_float2(0.f, 0.f);
  int run = 0;
  for (int n = n0; n < n1; ++n) {
    int g = batch[n];  // wave-uniform
    if (g != cur) {
      atomicAdd(&pool[(size_t)cur * HID + lane * 2 + 0], acc.x);
      atomicAdd(&pool[(size_t)cur * HID + lane * 2 + 1], acc.y);
      if (lane == 0) atomicAdd(&cnt[cur], run);
      acc = make_float2(0.f, 0.f);
      run = 0;
      cur = g;
    }
    float2 h = *(const float2*)&H[(size_t)n * HID + lane * 2];
    acc.x += h.x;
    acc.y += h.y;
    run += 1;
  }
  atomicAdd(&pool[(size_t)cur * HID + lane * 2 + 0], acc.x);
  atomicAdd(&pool[(size_t)cur * HID + lane * 2 + 1], acc.y);
  if (lane == 0) atomicAdd(&cnt[cur], run);
}

// ---------------- Final: sigmoid(pool/cnt @ Wlin + b) ----------------
__global__ __launch_bounds__(256) void final_k(const float* __restrict__ pool,
                                               const int* __restrict__ cnt,
                                               const float* __restrict__ Wlin,
                                               const float* __restrict__ blin,
                                               float* __restrict__ out) {
  int wave = threadIdx.x >> 6;
  int lane = threadIdx.x & 63;
  int g = blockIdx.x * 4 + wave;
  if (g >= NGRAPH) return;
  float2 p = *(const float2*)&pool[(size_t)g * HID + lane * 2];
  float v = p.x * Wlin[lane * 2 + 0] + p.y * Wlin[lane * 2 + 1];
#pragma unroll
  for (int off = 32; off; off >>= 1) v += __shfl_down(v, off, 64);
  if (lane == 0) {
    float c = (float)cnt[g];
    if (c < 1.f) c = 1.f;
    float logit = v / c + blin[0];
    out[g] = 1.f / (1.f + expf(-logit));
  }
}

extern "C" void kernel_launch(void* const* d_in, const int* in_sizes, int n_in,
                              void* d_out, int out_size, void* d_ws, size_t ws_size,
                              hipStream_t stream) {
  const float* x      = (const float*)d_in[0];
  const int*   ei     = (const int*)d_in[1];
  const int*   batch  = (const int*)d_in[2];
  const float* Wrel0  = (const float*)d_in[3];
  const float* brel0  = (const float*)d_in[4];
  const float* Wroot0 = (const float*)d_in[5];
  const float* Wrel1  = (const float*)d_in[6];
  const float* brel1  = (const float*)d_in[7];
  const float* Wroot1 = (const float*)d_in[8];
  const float* Wrel2  = (const float*)d_in[9];
  const float* brel2  = (const float*)d_in[10];
  const float* Wroot2 = (const float*)d_in[11];
  const float* Wlin   = (const float*)d_in[12];
  const float* blin   = (const float*)d_in[13];
  float* out = (float*)d_out;
  const int* srcp = ei;
  const int* dstp = ei + N_EDGES;

  char* ws = (char*)d_ws;
  size_t off = 0;
  auto alloc = [&](size_t b) { size_t o = off; off += (b + 255) & ~(size_t)255; return o; };
  u16*  Z     = (u16*)(ws + alloc(sizeof(u16) * N_NODES * HID));
  u16*  HA    = (u16*)(ws + alloc(sizeof(u16) * N_NODES * HID));
  u16*  HB    = (u16*)(ws + alloc(sizeof(u16) * N_NODES * HID));
  float* OUTF = (float*)(ws + alloc(sizeof(float) * N_NODES * HID));
  u16* WT1rel = (u16*)(ws + alloc(sizeof(u16) * HID * HID));
  u16* WT1root= (u16*)(ws + alloc(sizeof(u16) * HID * HID));
  u16* WT2rel = (u16*)(ws + alloc(sizeof(u16) * HID * HID));
  u16* WT2root= (u16*)(ws + alloc(sizeof(u16) * HID * HID));
  int* row_ptr  = (int*)(ws + alloc(sizeof(int) * (N_NODES + 1)));
  int* esrc     = (int*)(ws + alloc(sizeof(int) * N_EDGES));
  int* fill_off = (int*)(ws + alloc(sizeof(int) * N_NODES));
  int* bsum     = (int*)(ws + alloc(sizeof(int) * 256));
  int* boff     = (int*)(ws + alloc(sizeof(int) * 256));
  size_t zero_base = off;
  int* counts  = (int*)(ws + alloc(sizeof(int) * N_NODES));
  float* pool  = (float*)(ws + alloc(sizeof(float) * NGRAPH * HID));
  int* cnt     = (int*)(ws + alloc(sizeof(int) * NGRAPH));
  size_t zero_len = off - zero_base;

  hipMemsetAsync(ws + zero_base, 0, zero_len, stream);

  count_edges_k<<<(N_EDGES + 255) / 256, 256, 0, stream>>>(dstp, counts);
  partial_k<<<SCAN_NBLK, 256, 0, stream>>>(counts, bsum);
  scanb_k<<<1, 256, 0, stream>>>(bsum, boff, row_ptr);
  write_scan_k<<<SCAN_NBLK, 256, 0, stream>>>(counts, boff, row_ptr, fill_off);
  fill_edges_k<<<(N_EDGES + 255) / 256, 256, 0, stream>>>(srcp, dstp, fill_off, esrc);

  // Weight prep (bf16, transposed to B-fragment layout)
  prep_w_k<<<64, 256, 0, stream>>>(Wrel1, WT1rel);
  prep_w_k<<<64, 256, 0, stream>>>(Wroot1, WT1root);
  prep_w_k<<<64, 256, 0, stream>>>(Wrel2, WT2rel);
  prep_w_k<<<64, 256, 0, stream>>>(Wroot2, WT2root);

  // Layer 0
  proj0_k<<<(N_NODES * HID + 255) / 256, 256, 0, stream>>>(x, Wrel0, brel0, Wroot0, Z, HA);
  agg_k<<<(N_NODES + 3) / 4, 256, 0, stream>>>(Z, row_ptr, esrc, HA, 0);
  // Layer 1
  gemm_mfma_k<<<GEMM_NBLK, 256, 0, stream>>>(HA, WT1rel, WT1root, brel1, Z, HB, 0);
  agg_k<<<(N_NODES + 3) / 4, 256, 0, stream>>>(Z, row_ptr, esrc, HB, 0);
  // Layer 2
  gemm_mfma_k<<<GEMM_NBLK, 256, 0, stream>>>(HB, WT2rel, WT2root, brel2, Z, OUTF, 1);
  agg_k<<<(N_NODES + 3) / 4, 256, 0, stream>>>(Z, row_ptr, esrc, OUTF, 1);

  pool_seg_k<<<(POOL_NWAVE + 3) / 4, 256, 0, stream>>>(OUTF, batch, pool, cnt);
  final_k<<<(NGRAPH + 3) / 4, 256, 0, stream>>>(pool, cnt, Wlin, blin, out);
}

// Round 8
// 345.914 us; speedup vs baseline: 3.5739x; 1.1032x over previous
//
#include <hip/hip_runtime.h>
#include <hip/hip_bf16.h>
#include <math.h>

#define N_NODES 50000
#define N_EDGES 640000
#define IN_DIM 5
#define HID 128
#define NGRAPH 512
#define SCAN_NBLK ((N_NODES + 255) / 256)  // 196
#define POOL_CHUNK 64
#define POOL_NWAVE ((N_NODES + POOL_CHUNK - 1) / POOL_CHUNK)  // 782
#define GEMM_NBLK ((N_NODES + 63) / 64)    // 782

typedef unsigned short u16;
typedef __attribute__((ext_vector_type(8))) short bf16x8;
typedef __attribute__((ext_vector_type(8))) unsigned short u16x8;
typedef __attribute__((ext_vector_type(4))) float f32x4;
typedef __attribute__((ext_vector_type(8))) float f32x8;

__device__ __forceinline__ float bf2f(u16 u) {
  union { unsigned int i; float f; } v; v.i = ((unsigned int)u) << 16; return v.f;
}
__device__ __forceinline__ u16 f2bf(float f) {
  return __bfloat16_as_ushort(__float2bfloat16(f));
}

// ---------------- CSR build ----------------
__global__ void count_edges_k(const int* __restrict__ dst, int* __restrict__ counts) {
  int e = blockIdx.x * blockDim.x + threadIdx.x;
  if (e < N_EDGES) atomicAdd(&counts[dst[e]], 1);
}

__global__ __launch_bounds__(256) void partial_k(const int* __restrict__ counts,
                                                 int* __restrict__ bsum) {
  int t = threadIdx.x;
  int i = blockIdx.x * 256 + t;
  int v = (i < N_NODES) ? counts[i] : 0;
#pragma unroll
  for (int off = 32; off; off >>= 1) v += __shfl_down(v, off, 64);
  __shared__ int ws[4];
  if ((t & 63) == 0) ws[t >> 6] = v;
  __syncthreads();
  if (t == 0) bsum[blockIdx.x] = ws[0] + ws[1] + ws[2] + ws[3];
}

__global__ __launch_bounds__(256) void scanb_k(const int* __restrict__ bsum,
                                               int* __restrict__ boff,
                                               int* __restrict__ row_ptr) {
  __shared__ int s[256];
  int t = threadIdx.x;
  int v = (t < SCAN_NBLK) ? bsum[t] : 0;
  s[t] = v;
  __syncthreads();
#pragma unroll
  for (int off = 1; off < 256; off <<= 1) {
    int u = (t >= off) ? s[t - off] : 0;
    __syncthreads();
    s[t] += u;
    __syncthreads();
  }
  if (t < SCAN_NBLK) boff[t] = s[t] - v;
  if (t == 255) row_ptr[N_NODES] = s[255];
}

__global__ __launch_bounds__(256) void write_scan_k(const int* __restrict__ counts,
                                                    const int* __restrict__ boff,
                                                    int* __restrict__ row_ptr,
                                                    int* __restrict__ fill_off) {
  __shared__ int s[256];
  int t = threadIdx.x;
  int i = blockIdx.x * 256 + t;
  int c = (i < N_NODES) ? counts[i] : 0;
  s[t] = c;
  __syncthreads();
#pragma unroll
  for (int off = 1; off < 256; off <<= 1) {
    int u = (t >= off) ? s[t - off] : 0;
    __syncthreads();
    s[t] += u;
    __syncthreads();
  }
  int excl = s[t] - c + boff[blockIdx.x];
  if (i < N_NODES) {
    row_ptr[i] = excl;
    fill_off[i] = excl;
  }
}

__global__ void fill_edges_k(const int* __restrict__ src, const int* __restrict__ dst,
                             int* __restrict__ fill_off, int* __restrict__ esrc) {
  int e = blockIdx.x * blockDim.x + threadIdx.x;
  if (e < N_EDGES) {
    int d = dst[e];
    int pos = atomicAdd(&fill_off[d], 1);
    esrc[pos] = src[e];
  }
}

// ---------------- Weight prep: 4x (W f32 [k][n] -> WT bf16 [n][k]) in one launch ----
__global__ __launch_bounds__(256) void prep_w4_k(const float* __restrict__ W0,
                                                 const float* __restrict__ W1,
                                                 const float* __restrict__ W2,
                                                 const float* __restrict__ W3,
                                                 u16* __restrict__ T0, u16* __restrict__ T1,
                                                 u16* __restrict__ T2, u16* __restrict__ T3) {
  int which = blockIdx.x >> 6;
  int idx = (blockIdx.x & 63) * 256 + threadIdx.x;  // k*128 + n
  const float* W = which == 0 ? W0 : which == 1 ? W1 : which == 2 ? W2 : W3;
  u16* T = which == 0 ? T0 : which == 1 ? T1 : which == 2 ? T2 : T3;
  int k = idx >> 7, n = idx & 127;
  T[n * HID + k] = f2bf(W[idx]);
}

// ---------------- Layer 0 rel projection only (IN_DIM=5); Z bf16 ----------------
__global__ void proj0_k(const float* __restrict__ x, const float* __restrict__ Wrel,
                        u16* __restrict__ Z) {
  int idx = blockIdx.x * blockDim.x + threadIdx.x;  // node*128 + c
  if (idx >= N_NODES * HID) return;
  int i = idx >> 7, c = idx & 127;
  float zr = 0.f;
#pragma unroll
  for (int k = 0; k < IN_DIM; ++k) zr = fmaf(x[i * IN_DIM + k], Wrel[k * HID + c], zr);
  Z[idx] = f2bf(zr);
}

// ---------------- MFMA GEMM for layers 1,2 ----------------
__global__ __launch_bounds__(256, 3) void gemm_mfma_k(const u16* __restrict__ A,
                                                      const u16* __restrict__ WrelT,
                                                      const u16* __restrict__ WrootT,
                                                      const float* __restrict__ bias,
                                                      u16* __restrict__ Z,
                                                      void* __restrict__ R,
                                                      int r_is_f32) {
  __shared__ u16 As[64][136];  // pad +8 bf16 -> 2-way max bank aliasing (free)
  int tid = threadIdx.x;
  int wv = tid >> 6, lane = tid & 63;
  int m = lane & 15, quad = lane >> 4;
  int r0 = blockIdx.x * 64;

#pragma unroll
  for (int it = 0; it < 4; ++it) {
    int idx = it * 256 + tid;
    int row = idx >> 4, q = idx & 15;
    int grow = r0 + row;
    float4 v = make_float4(0.f, 0.f, 0.f, 0.f);
    if (grow < N_NODES) v = *(const float4*)(A + (size_t)grow * HID + q * 8);
    *(float4*)&As[row][q * 8] = v;
  }
  __syncthreads();

  const u16* WT = (wv < 2) ? WrelT : WrootT;
  int n0 = (wv & 1) * 64;

  f32x4 acc[4][4];
#pragma unroll
  for (int mt = 0; mt < 4; ++mt)
#pragma unroll
    for (int nt = 0; nt < 4; ++nt) acc[mt][nt] = (f32x4){0.f, 0.f, 0.f, 0.f};

#pragma unroll
  for (int ks = 0; ks < 4; ++ks) {
    int kb = ks * 32;
    bf16x8 af[4], bf[4];
#pragma unroll
    for (int mt = 0; mt < 4; ++mt)
      af[mt] = *(const bf16x8*)&As[mt * 16 + m][kb + quad * 8];
#pragma unroll
    for (int nt = 0; nt < 4; ++nt)
      bf[nt] = *(const bf16x8*)(WT + (size_t)(n0 + nt * 16 + m) * HID + kb + quad * 8);
#pragma unroll
    for (int mt = 0; mt < 4; ++mt)
#pragma unroll
      for (int nt = 0; nt < 4; ++nt)
        acc[mt][nt] = __builtin_amdgcn_mfma_f32_16x16x32_bf16(af[mt], bf[nt], acc[mt][nt], 0, 0, 0);
  }

  // Epilogue. C/D layout: col = lane&15, row = quad*4 + reg.
  if (wv < 2) {
#pragma unroll
    for (int mt = 0; mt < 4; ++mt) {
#pragma unroll
      for (int nt = 0; nt < 4; ++nt) {
        int col = n0 + nt * 16 + m;
#pragma unroll
        for (int r = 0; r < 4; ++r) {
          int row = r0 + mt * 16 + quad * 4 + r;
          if (row < N_NODES) Z[(size_t)row * HID + col] = f2bf(acc[mt][nt][r]);
        }
      }
    }
  } else {
    float bl[4];
#pragma unroll
    for (int nt = 0; nt < 4; ++nt) bl[nt] = bias[n0 + nt * 16 + m];
#pragma unroll
    for (int mt = 0; mt < 4; ++mt) {
#pragma unroll
      for (int nt = 0; nt < 4; ++nt) {
        int col = n0 + nt * 16 + m;
#pragma unroll
        for (int r = 0; r < 4; ++r) {
          int row = r0 + mt * 16 + quad * 4 + r;
          if (row < N_NODES) {
            float v = acc[mt][nt][r] + bl[nt];
            if (r_is_f32) ((float*)R)[(size_t)row * HID + col] = v;
            else          ((u16*)R)[(size_t)row * HID + col] = f2bf(v);
          }
        }
      }
    }
  }
}

// ---------------- Edge aggregation, 4 edges in flight ----------------
// Wave per node; quarter q=lane>>4 handles edges e=beg+q, beg+q+4, ...
// Each lane loads ushort8 (16B) of Z; quarters combined via shfl_xor(16,32).
// mode 0: OUT bf16 rmw + ReLU.  mode 1: OUT f32 rmw, no act.
// mode 2 (layer 0): OUT bf16 = relu(x@Wroot0 + b0 + gather) computed inline.
__global__ __launch_bounds__(256) void agg_k(const u16* __restrict__ Z,
                                             const int* __restrict__ row_ptr,
                                             const int* __restrict__ esrc,
                                             void* __restrict__ OUT, int mode,
                                             const float* __restrict__ x,
                                             const float* __restrict__ Wroot,
                                             const float* __restrict__ bias) {
  int wave = threadIdx.x >> 6;
  int lane = threadIdx.x & 63;
  int node = blockIdx.x * 4 + wave;
  if (node >= N_NODES) return;
  int q = lane >> 4;        // 0..3
  int f8 = (lane & 15) * 8; // feature base (8 features/lane)
  int beg = row_ptr[node], end = row_ptr[node + 1];
  f32x8 acc;
#pragma unroll
  for (int j = 0; j < 8; ++j) acc[j] = 0.f;
  for (int e = beg + q; e < end; e += 4) {
    int s = esrc[e];
    u16x8 z8 = *(const u16x8*)(Z + (size_t)s * HID + f8);
#pragma unroll
    for (int j = 0; j < 8; ++j) acc[j] += bf2f(z8[j]);
  }
#pragma unroll
  for (int j = 0; j < 8; ++j) {
    acc[j] += __shfl_xor(acc[j], 16, 64);
    acc[j] += __shfl_xor(acc[j], 32, 64);
  }
  if (q == 0) {
    if (mode == 0) {
      u16* o = (u16*)OUT + (size_t)node * HID + f8;
      u16x8 o8 = *(const u16x8*)o;
      u16x8 w8;
#pragma unroll
      for (int j = 0; j < 8; ++j) w8[j] = f2bf(fmaxf(bf2f(o8[j]) + acc[j], 0.f));
      *(u16x8*)o = w8;
    } else if (mode == 1) {
      float* o = (float*)OUT + (size_t)node * HID + f8;
      float4 a = *(const float4*)o;
      float4 b = *(const float4*)(o + 4);
      a.x += acc[0]; a.y += acc[1]; a.z += acc[2]; a.w += acc[3];
      b.x += acc[4]; b.y += acc[5]; b.z += acc[6]; b.w += acc[7];
      *(float4*)o = a;
      *(float4*)(o + 4) = b;
    } else {
      float xr[IN_DIM];
#pragma unroll
      for (int k = 0; k < IN_DIM; ++k) xr[k] = x[node * IN_DIM + k];
      u16x8 w8;
#pragma unroll
      for (int j = 0; j < 8; ++j) {
        float r = bias[f8 + j];
#pragma unroll
        for (int k = 0; k < IN_DIM; ++k) r = fmaf(xr[k], Wroot[k * HID + f8 + j], r);
        w8[j] = f2bf(fmaxf(r + acc[j], 0.f));
      }
      *(u16x8*)((u16*)OUT + (size_t)node * HID + f8) = w8;
    }
  }
}

// ---------------- Mean pool: segmented reduction over SORTED batch ids ----------------
__global__ __launch_bounds__(256) void pool_seg_k(const float* __restrict__ H,
                                                  const int* __restrict__ batch,
                                                  float* __restrict__ pool,
                                                  int* __restrict__ cnt) {
  int wave = blockIdx.x * 4 + (threadIdx.x >> 6);
  int lane = threadIdx.x & 63;
  if (wave >= POOL_NWAVE) return;
  int n0 = wave * POOL_CHUNK;
  int n1 = n0 + POOL_CHUNK;
  if (n1 > N_NODES) n1 = N_NODES;
  int cur = batch[n0];
  float2 acc = make_float2(0.f, 0.f);
  int run = 0;
  for (int n = n0; n < n1; ++n) {
    int g = batch[n];  // wave-uniform
    if (g != cur) {
      atomicAdd(&pool[(size_t)cur * HID + lane * 2 + 0], acc.x);
      atomicAdd(&pool[(size_t)cur * HID + lane * 2 + 1], acc.y);
      if (lane == 0) atomicAdd(&cnt[cur], run);
      acc = make_float2(0.f, 0.f);
      run = 0;
      cur = g;
    }
    float2 h = *(const float2*)&H[(size_t)n * HID + lane * 2];
    acc.x += h.x;
    acc.y += h.y;
    run += 1;
  }
  atomicAdd(&pool[(size_t)cur * HID + lane * 2 + 0], acc.x);
  atomicAdd(&pool[(size_t)cur * HID + lane * 2 + 1], acc.y);
  if (lane == 0) atomicAdd(&cnt[cur], run);
}

// ---------------- Final: sigmoid(pool/cnt @ Wlin + b) ----------------
__global__ __launch_bounds__(256) void final_k(const float* __restrict__ pool,
                                               const int* __restrict__ cnt,
                                               const float* __restrict__ Wlin,
                                               const float* __restrict__ blin,
                                               float* __restrict__ out) {
  int wave = threadIdx.x >> 6;
  int lane = threadIdx.x & 63;
  int g = blockIdx.x * 4 + wave;
  if (g >= NGRAPH) return;
  float2 p = *(const float2*)&pool[(size_t)g * HID + lane * 2];
  float v = p.x * Wlin[lane * 2 + 0] + p.y * Wlin[lane * 2 + 1];
#pragma unroll
  for (int off = 32; off; off >>= 1) v += __shfl_down(v, off, 64);
  if (lane == 0) {
    float c = (float)cnt[g];
    if (c < 1.f) c = 1.f;
    float logit = v / c + blin[0];
    out[g] = 1.f / (1.f + expf(-logit));
  }
}

extern "C" void kernel_launch(void* const* d_in, const int* in_sizes, int n_in,
                              void* d_out, int out_size, void* d_ws, size_t ws_size,
                              hipStream_t stream) {
  const float* x      = (const float*)d_in[0];
  const int*   ei     = (const int*)d_in[1];
  const int*   batch  = (const int*)d_in[2];
  const float* Wrel0  = (const float*)d_in[3];
  const float* brel0  = (const float*)d_in[4];
  const float* Wroot0 = (const float*)d_in[5];
  const float* Wrel1  = (const float*)d_in[6];
  const float* brel1  = (const float*)d_in[7];
  const float* Wroot1 = (const float*)d_in[8];
  const float* Wrel2  = (const float*)d_in[9];
  const float* brel2  = (const float*)d_in[10];
  const float* Wroot2 = (const float*)d_in[11];
  const float* Wlin   = (const float*)d_in[12];
  const float* blin   = (const float*)d_in[13];
  float* out = (float*)d_out;
  const int* srcp = ei;
  const int* dstp = ei + N_EDGES;

  char* ws = (char*)d_ws;
  size_t off = 0;
  auto alloc = [&](size_t b) { size_t o = off; off += (b + 255) & ~(size_t)255; return o; };
  u16*  Z     = (u16*)(ws + alloc(sizeof(u16) * N_NODES * HID));
  u16*  HA    = (u16*)(ws + alloc(sizeof(u16) * N_NODES * HID));
  u16*  HB    = (u16*)(ws + alloc(sizeof(u16) * N_NODES * HID));
  float* OUTF = (float*)(ws + alloc(sizeof(float) * N_NODES * HID));
  u16* WT1rel = (u16*)(ws + alloc(sizeof(u16) * HID * HID));
  u16* WT1root= (u16*)(ws + alloc(sizeof(u16) * HID * HID));
  u16* WT2rel = (u16*)(ws + alloc(sizeof(u16) * HID * HID));
  u16* WT2root= (u16*)(ws + alloc(sizeof(u16) * HID * HID));
  int* row_ptr  = (int*)(ws + alloc(sizeof(int) * (N_NODES + 1)));
  int* esrc     = (int*)(ws + alloc(sizeof(int) * N_EDGES));
  int* fill_off = (int*)(ws + alloc(sizeof(int) * N_NODES));
  int* bsum     = (int*)(ws + alloc(sizeof(int) * 256));
  int* boff     = (int*)(ws + alloc(sizeof(int) * 256));
  size_t zero_base = off;
  int* counts  = (int*)(ws + alloc(sizeof(int) * N_NODES));
  float* pool  = (float*)(ws + alloc(sizeof(float) * NGRAPH * HID));
  int* cnt     = (int*)(ws + alloc(sizeof(int) * NGRAPH));
  size_t zero_len = off - zero_base;

  hipMemsetAsync(ws + zero_base, 0, zero_len, stream);

  count_edges_k<<<(N_EDGES + 255) / 256, 256, 0, stream>>>(dstp, counts);
  partial_k<<<SCAN_NBLK, 256, 0, stream>>>(counts, bsum);
  scanb_k<<<1, 256, 0, stream>>>(bsum, boff, row_ptr);
  write_scan_k<<<SCAN_NBLK, 256, 0, stream>>>(counts, boff, row_ptr, fill_off);
  fill_edges_k<<<(N_EDGES + 255) / 256, 256, 0, stream>>>(srcp, dstp, fill_off, esrc);

  prep_w4_k<<<256, 256, 0, stream>>>(Wrel1, Wroot1, Wrel2, Wroot2,
                                     WT1rel, WT1root, WT2rel, WT2root);

  // Layer 0: Z = x@Wrel0 (bf16); agg mode 2 computes root-init inline
  proj0_k<<<(N_NODES * HID + 255) / 256, 256, 0, stream>>>(x, Wrel0, Z);
  agg_k<<<(N_NODES + 3) / 4, 256, 0, stream>>>(Z, row_ptr, esrc, HA, 2, x, Wroot0, brel0);
  // Layer 1
  gemm_mfma_k<<<GEMM_NBLK, 256, 0, stream>>>(HA, WT1rel, WT1root, brel1, Z, HB, 0);
  agg_k<<<(N_NODES + 3) / 4, 256, 0, stream>>>(Z, row_ptr, esrc, HB, 0, nullptr, nullptr, nullptr);
  // Layer 2
  gemm_mfma_k<<<GEMM_NBLK, 256, 0, stream>>>(HB, WT2rel, WT2root, brel2, Z, OUTF, 1);
  agg_k<<<(N_NODES + 3) / 4, 256, 0, stream>>>(Z, row_ptr, esrc, OUTF, 1, nullptr, nullptr, nullptr);

  pool_seg_k<<<(POOL_NWAVE + 3) / 4, 256, 0, stream>>>(OUTF, batch, pool, cnt);
  final_k<<<(NGRAPH + 3) / 4, 256, 0, stream>>>(pool, cnt, Wlin, blin, out);
}

// Round 9
// 339.560 us; speedup vs baseline: 3.6407x; 1.0187x over previous
//
#include <hip/hip_runtime.h>
#include <hip/hip_bf16.h>
#include <math.h>

#define N_NODES 50000
#define N_EDGES 640000
#define IN_DIM 5
#define HID 128
#define NGRAPH 512
#define SCAN_NBLK ((N_NODES + 255) / 256)  // 196
#define GEMM_NBLK ((N_NODES + 63) / 64)    // 782
#define PCHUNK 16
#define PNW ((N_NODES + PCHUNK - 1) / PCHUNK)  // 3125

typedef unsigned short u16;
typedef __attribute__((ext_vector_type(8))) short bf16x8;
typedef __attribute__((ext_vector_type(8))) unsigned short u16x8;
typedef __attribute__((ext_vector_type(4))) float f32x4;
typedef __attribute__((ext_vector_type(8))) float f32x8;

__device__ __forceinline__ float bf2f(u16 u) {
  union { unsigned int i; float f; } v; v.i = ((unsigned int)u) << 16; return v.f;
}
__device__ __forceinline__ u16 f2bf(float f) {
  return __bfloat16_as_ushort(__float2bfloat16(f));
}

// ---------------- CSR build ----------------
__global__ void count_edges_k(const int* __restrict__ dst, int* __restrict__ counts) {
  int e = blockIdx.x * blockDim.x + threadIdx.x;
  if (e < N_EDGES) atomicAdd(&counts[dst[e]], 1);
}

__global__ __launch_bounds__(256) void partial_k(const int* __restrict__ counts,
                                                 int* __restrict__ bsum) {
  int t = threadIdx.x;
  int i = blockIdx.x * 256 + t;
  int v = (i < N_NODES) ? counts[i] : 0;
#pragma unroll
  for (int off = 32; off; off >>= 1) v += __shfl_down(v, off, 64);
  __shared__ int ws[4];
  if ((t & 63) == 0) ws[t >> 6] = v;
  __syncthreads();
  if (t == 0) bsum[blockIdx.x] = ws[0] + ws[1] + ws[2] + ws[3];
}

__global__ __launch_bounds__(256) void scanb_k(const int* __restrict__ bsum,
                                               int* __restrict__ boff,
                                               int* __restrict__ row_ptr) {
  __shared__ int s[256];
  int t = threadIdx.x;
  int v = (t < SCAN_NBLK) ? bsum[t] : 0;
  s[t] = v;
  __syncthreads();
#pragma unroll
  for (int off = 1; off < 256; off <<= 1) {
    int u = (t >= off) ? s[t - off] : 0;
    __syncthreads();
    s[t] += u;
    __syncthreads();
  }
  if (t < SCAN_NBLK) boff[t] = s[t] - v;
  if (t == 255) row_ptr[N_NODES] = s[255];
}

__global__ __launch_bounds__(256) void write_scan_k(const int* __restrict__ counts,
                                                    const int* __restrict__ boff,
                                                    int* __restrict__ row_ptr,
                                                    int* __restrict__ fill_off) {
  __shared__ int s[256];
  int t = threadIdx.x;
  int i = blockIdx.x * 256 + t;
  int c = (i < N_NODES) ? counts[i] : 0;
  s[t] = c;
  __syncthreads();
#pragma unroll
  for (int off = 1; off < 256; off <<= 1) {
    int u = (t >= off) ? s[t - off] : 0;
    __syncthreads();
    s[t] += u;
    __syncthreads();
  }
  int excl = s[t] - c + boff[blockIdx.x];
  if (i < N_NODES) {
    row_ptr[i] = excl;
    fill_off[i] = excl;
  }
}

__global__ void fill_edges_k(const int* __restrict__ src, const int* __restrict__ dst,
                             int* __restrict__ fill_off, int* __restrict__ esrc) {
  int e = blockIdx.x * blockDim.x + threadIdx.x;
  if (e < N_EDGES) {
    int d = dst[e];
    int pos = atomicAdd(&fill_off[d], 1);
    esrc[pos] = src[e];
  }
}

// ---------------- Weight prep: 4x (W f32 [k][n] -> WT bf16 [n][k]) in one launch ----
__global__ __launch_bounds__(256) void prep_w4_k(const float* __restrict__ W0,
                                                 const float* __restrict__ W1,
                                                 const float* __restrict__ W2,
                                                 const float* __restrict__ W3,
                                                 u16* __restrict__ T0, u16* __restrict__ T1,
                                                 u16* __restrict__ T2, u16* __restrict__ T3) {
  int which = blockIdx.x >> 6;
  int idx = (blockIdx.x & 63) * 256 + threadIdx.x;  // k*128 + n
  const float* W = which == 0 ? W0 : which == 1 ? W1 : which == 2 ? W2 : W3;
  u16* T = which == 0 ? T0 : which == 1 ? T1 : which == 2 ? T2 : T3;
  int k = idx >> 7, n = idx & 127;
  T[n * HID + k] = f2bf(W[idx]);
}

// ---------------- Layer 0 rel projection only (IN_DIM=5); Z bf16 ----------------
__global__ void proj0_k(const float* __restrict__ x, const float* __restrict__ Wrel,
                        u16* __restrict__ Z) {
  int idx = blockIdx.x * blockDim.x + threadIdx.x;  // node*128 + c
  if (idx >= N_NODES * HID) return;
  int i = idx >> 7, c = idx & 127;
  float zr = 0.f;
#pragma unroll
  for (int k = 0; k < IN_DIM; ++k) zr = fmaf(x[i * IN_DIM + k], Wrel[k * HID + c], zr);
  Z[idx] = f2bf(zr);
}

// ---------------- MFMA GEMM for layers 1,2 ----------------
__global__ __launch_bounds__(256, 3) void gemm_mfma_k(const u16* __restrict__ A,
                                                      const u16* __restrict__ WrelT,
                                                      const u16* __restrict__ WrootT,
                                                      const float* __restrict__ bias,
                                                      u16* __restrict__ Z,
                                                      void* __restrict__ R,
                                                      int r_is_f32) {
  __shared__ u16 As[64][136];  // pad +8 bf16 -> 2-way max bank aliasing (free)
  int tid = threadIdx.x;
  int wv = tid >> 6, lane = tid & 63;
  int m = lane & 15, quad = lane >> 4;
  int r0 = blockIdx.x * 64;

#pragma unroll
  for (int it = 0; it < 4; ++it) {
    int idx = it * 256 + tid;
    int row = idx >> 4, q = idx & 15;
    int grow = r0 + row;
    float4 v = make_float4(0.f, 0.f, 0.f, 0.f);
    if (grow < N_NODES) v = *(const float4*)(A + (size_t)grow * HID + q * 8);
    *(float4*)&As[row][q * 8] = v;
  }
  __syncthreads();

  const u16* WT = (wv < 2) ? WrelT : WrootT;
  int n0 = (wv & 1) * 64;

  f32x4 acc[4][4];
#pragma unroll
  for (int mt = 0; mt < 4; ++mt)
#pragma unroll
    for (int nt = 0; nt < 4; ++nt) acc[mt][nt] = (f32x4){0.f, 0.f, 0.f, 0.f};

#pragma unroll
  for (int ks = 0; ks < 4; ++ks) {
    int kb = ks * 32;
    bf16x8 af[4], bf[4];
#pragma unroll
    for (int mt = 0; mt < 4; ++mt)
      af[mt] = *(const bf16x8*)&As[mt * 16 + m][kb + quad * 8];
#pragma unroll
    for (int nt = 0; nt < 4; ++nt)
      bf[nt] = *(const bf16x8*)(WT + (size_t)(n0 + nt * 16 + m) * HID + kb + quad * 8);
#pragma unroll
    for (int mt = 0; mt < 4; ++mt)
#pragma unroll
      for (int nt = 0; nt < 4; ++nt)
        acc[mt][nt] = __builtin_amdgcn_mfma_f32_16x16x32_bf16(af[mt], bf[nt], acc[mt][nt], 0, 0, 0);
  }

  // Epilogue. C/D layout: col = lane&15, row = quad*4 + reg.
  if (wv < 2) {
#pragma unroll
    for (int mt = 0; mt < 4; ++mt) {
#pragma unroll
      for (int nt = 0; nt < 4; ++nt) {
        int col = n0 + nt * 16 + m;
#pragma unroll
        for (int r = 0; r < 4; ++r) {
          int row = r0 + mt * 16 + quad * 4 + r;
          if (row < N_NODES) Z[(size_t)row * HID + col] = f2bf(acc[mt][nt][r]);
        }
      }
    }
  } else {
    float bl[4];
#pragma unroll
    for (int nt = 0; nt < 4; ++nt) bl[nt] = bias[n0 + nt * 16 + m];
#pragma unroll
    for (int mt = 0; mt < 4; ++mt) {
#pragma unroll
      for (int nt = 0; nt < 4; ++nt) {
        int col = n0 + nt * 16 + m;
#pragma unroll
        for (int r = 0; r < 4; ++r) {
          int row = r0 + mt * 16 + quad * 4 + r;
          if (row < N_NODES) {
            float v = acc[mt][nt][r] + bl[nt];
            if (r_is_f32) ((float*)R)[(size_t)row * HID + col] = v;
            else          ((u16*)R)[(size_t)row * HID + col] = f2bf(v);
          }
        }
      }
    }
  }
}

// ---- gather helper: unrolled x2, 8 edges in flight per wave ----
__device__ __forceinline__ void gather_node(const u16* __restrict__ Z,
                                            const int* __restrict__ esrc,
                                            int beg, int end, int q, int f8,
                                            f32x8& out) {
  f32x8 a0, a1;
#pragma unroll
  for (int j = 0; j < 8; ++j) { a0[j] = 0.f; a1[j] = 0.f; }
  int e = beg + q;
  for (; e + 4 < end; e += 8) {
    int s0 = esrc[e];
    int s1 = esrc[e + 4];
    u16x8 za = *(const u16x8*)(Z + (size_t)s0 * HID + f8);
    u16x8 zb = *(const u16x8*)(Z + (size_t)s1 * HID + f8);
#pragma unroll
    for (int j = 0; j < 8; ++j) { a0[j] += bf2f(za[j]); a1[j] += bf2f(zb[j]); }
  }
  if (e < end) {
    int s0 = esrc[e];
    u16x8 za = *(const u16x8*)(Z + (size_t)s0 * HID + f8);
#pragma unroll
    for (int j = 0; j < 8; ++j) a0[j] += bf2f(za[j]);
  }
#pragma unroll
  for (int j = 0; j < 8; ++j) out[j] = a0[j] + a1[j];
}

// ---------------- Edge aggregation (layers 0,1), OUT bf16 + ReLU ----------------
// mode 0: OUT bf16 rmw + ReLU.  mode 2: OUT = relu(x@Wroot0 + b0 + gather).
__global__ __launch_bounds__(256) void agg_k(const u16* __restrict__ Z,
                                             const int* __restrict__ row_ptr,
                                             const int* __restrict__ esrc,
                                             u16* __restrict__ OUT, int mode,
                                             const float* __restrict__ x,
                                             const float* __restrict__ Wroot,
                                             const float* __restrict__ bias) {
  int wave = threadIdx.x >> 6;
  int lane = threadIdx.x & 63;
  int node = blockIdx.x * 4 + wave;
  if (node >= N_NODES) return;
  int q = lane >> 4;        // 0..3
  int f8 = (lane & 15) * 8; // 8 features/lane
  int beg = row_ptr[node], end = row_ptr[node + 1];
  f32x8 acc;
  gather_node(Z, esrc, beg, end, q, f8, acc);
#pragma unroll
  for (int j = 0; j < 8; ++j) {
    acc[j] += __shfl_xor(acc[j], 16, 64);
    acc[j] += __shfl_xor(acc[j], 32, 64);
  }
  if (q == 0) {
    u16* o = OUT + (size_t)node * HID + f8;
    u16x8 w8;
    if (mode == 0) {
      u16x8 o8 = *(const u16x8*)o;
#pragma unroll
      for (int j = 0; j < 8; ++j) w8[j] = f2bf(fmaxf(bf2f(o8[j]) + acc[j], 0.f));
    } else {
      float xr[IN_DIM];
#pragma unroll
      for (int k = 0; k < IN_DIM; ++k) xr[k] = x[node * IN_DIM + k];
#pragma unroll
      for (int j = 0; j < 8; ++j) {
        float r = bias[f8 + j];
#pragma unroll
        for (int k = 0; k < IN_DIM; ++k) r = fmaf(xr[k], Wroot[k * HID + f8 + j], r);
        w8[j] = f2bf(fmaxf(r + acc[j], 0.f));
      }
    }
    *(u16x8*)o = w8;
  }
}

// ---------------- Fused layer-2 agg + mean pool ----------------
// Layer 2 has no activation, so pool[g] = sum_i (root2_i + gather_i) needs no
// per-node materialization. Wave walks PCHUNK sorted nodes, gathers Z per node
// (8 edges in flight), adds ROOT f32 row, accumulates pool in registers,
// flushes atomics only at graph boundaries.
__global__ __launch_bounds__(256) void pool_fused_k(const u16* __restrict__ Z,
                                                    const float* __restrict__ ROOT,
                                                    const int* __restrict__ row_ptr,
                                                    const int* __restrict__ esrc,
                                                    const int* __restrict__ batch,
                                                    float* __restrict__ pool,
                                                    int* __restrict__ cnt) {
  int wave = blockIdx.x * 4 + (threadIdx.x >> 6);
  int lane = threadIdx.x & 63;
  if (wave >= PNW) return;
  int q = lane >> 4;
  int f8 = (lane & 15) * 8;
  int n0 = wave * PCHUNK;
  int n1 = n0 + PCHUNK;
  if (n1 > N_NODES) n1 = N_NODES;
  int cur = batch[n0];
  int run = 0;
  float pacc[8];
#pragma unroll
  for (int j = 0; j < 8; ++j) pacc[j] = 0.f;

  for (int n = n0; n < n1; ++n) {
    int g = batch[n];  // wave-uniform
    if (g != cur) {
      if (q == 0) {
#pragma unroll
        for (int j = 0; j < 8; ++j) atomicAdd(&pool[(size_t)cur * HID + f8 + j], pacc[j]);
      }
      if (lane == 0) atomicAdd(&cnt[cur], run);
#pragma unroll
      for (int j = 0; j < 8; ++j) pacc[j] = 0.f;
      run = 0;
      cur = g;
    }
    int beg = row_ptr[n], end = row_ptr[n + 1];
    f32x8 acc;
    gather_node(Z, esrc, beg, end, q, f8, acc);
#pragma unroll
    for (int j = 0; j < 8; ++j) {
      acc[j] += __shfl_xor(acc[j], 16, 64);
      acc[j] += __shfl_xor(acc[j], 32, 64);
    }
    if (q == 0) {
      const float* rp = ROOT + (size_t)n * HID + f8;
      float4 ra = *(const float4*)rp;
      float4 rb = *(const float4*)(rp + 4);
      pacc[0] += acc[0] + ra.x; pacc[1] += acc[1] + ra.y;
      pacc[2] += acc[2] + ra.z; pacc[3] += acc[3] + ra.w;
      pacc[4] += acc[4] + rb.x; pacc[5] += acc[5] + rb.y;
      pacc[6] += acc[6] + rb.z; pacc[7] += acc[7] + rb.w;
    }
    run += 1;
  }
  if (q == 0) {
#pragma unroll
    for (int j = 0; j < 8; ++j) atomicAdd(&pool[(size_t)cur * HID + f8 + j], pacc[j]);
  }
  if (lane == 0) atomicAdd(&cnt[cur], run);
}

// ---------------- Final: sigmoid(pool/cnt @ Wlin + b) ----------------
__global__ __launch_bounds__(256) void final_k(const float* __restrict__ pool,
                                               const int* __restrict__ cnt,
                                               const float* __restrict__ Wlin,
                                               const float* __restrict__ blin,
                                               float* __restrict__ out) {
  int wave = threadIdx.x >> 6;
  int lane = threadIdx.x & 63;
  int g = blockIdx.x * 4 + wave;
  if (g >= NGRAPH) return;
  float2 p = *(const float2*)&pool[(size_t)g * HID + lane * 2];
  float v = p.x * Wlin[lane * 2 + 0] + p.y * Wlin[lane * 2 + 1];
#pragma unroll
  for (int off = 32; off; off >>= 1) v += __shfl_down(v, off, 64);
  if (lane == 0) {
    float c = (float)cnt[g];
    if (c < 1.f) c = 1.f;
    float logit = v / c + blin[0];
    out[g] = 1.f / (1.f + expf(-logit));
  }
}

extern "C" void kernel_launch(void* const* d_in, const int* in_sizes, int n_in,
                              void* d_out, int out_size, void* d_ws, size_t ws_size,
                              hipStream_t stream) {
  const float* x      = (const float*)d_in[0];
  const int*   ei     = (const int*)d_in[1];
  const int*   batch  = (const int*)d_in[2];
  const float* Wrel0  = (const float*)d_in[3];
  const float* brel0  = (const float*)d_in[4];
  const float* Wroot0 = (const float*)d_in[5];
  const float* Wrel1  = (const float*)d_in[6];
  const float* brel1  = (const float*)d_in[7];
  const float* Wroot1 = (const float*)d_in[8];
  const float* Wrel2  = (const float*)d_in[9];
  const float* brel2  = (const float*)d_in[10];
  const float* Wroot2 = (const float*)d_in[11];
  const float* Wlin   = (const float*)d_in[12];
  const float* blin   = (const float*)d_in[13];
  float* out = (float*)d_out;
  const int* srcp = ei;
  const int* dstp = ei + N_EDGES;

  char* ws = (char*)d_ws;
  size_t off = 0;
  auto alloc = [&](size_t b) { size_t o = off; off += (b + 255) & ~(size_t)255; return o; };
  u16*  Z     = (u16*)(ws + alloc(sizeof(u16) * N_NODES * HID));
  u16*  HA    = (u16*)(ws + alloc(sizeof(u16) * N_NODES * HID));
  u16*  HB    = (u16*)(ws + alloc(sizeof(u16) * N_NODES * HID));
  float* OUTF = (float*)(ws + alloc(sizeof(float) * N_NODES * HID));
  u16* WT1rel = (u16*)(ws + alloc(sizeof(u16) * HID * HID));
  u16* WT1root= (u16*)(ws + alloc(sizeof(u16) * HID * HID));
  u16* WT2rel = (u16*)(ws + alloc(sizeof(u16) * HID * HID));
  u16* WT2root= (u16*)(ws + alloc(sizeof(u16) * HID * HID));
  int* row_ptr  = (int*)(ws + alloc(sizeof(int) * (N_NODES + 1)));
  int* esrc     = (int*)(ws + alloc(sizeof(int) * N_EDGES));
  int* fill_off = (int*)(ws + alloc(sizeof(int) * N_NODES));
  int* bsum     = (int*)(ws + alloc(sizeof(int) * 256));
  int* boff     = (int*)(ws + alloc(sizeof(int) * 256));
  size_t zero_base = off;
  int* counts  = (int*)(ws + alloc(sizeof(int) * N_NODES));
  float* pool  = (float*)(ws + alloc(sizeof(float) * NGRAPH * HID));
  int* cnt     = (int*)(ws + alloc(sizeof(int) * NGRAPH));
  size_t zero_len = off - zero_base;

  hipMemsetAsync(ws + zero_base, 0, zero_len, stream);

  count_edges_k<<<(N_EDGES + 255) / 256, 256, 0, stream>>>(dstp, counts);
  partial_k<<<SCAN_NBLK, 256, 0, stream>>>(counts, bsum);
  scanb_k<<<1, 256, 0, stream>>>(bsum, boff, row_ptr);
  write_scan_k<<<SCAN_NBLK, 256, 0, stream>>>(counts, boff, row_ptr, fill_off);
  fill_edges_k<<<(N_EDGES + 255) / 256, 256, 0, stream>>>(srcp, dstp, fill_off, esrc);

  prep_w4_k<<<256, 256, 0, stream>>>(Wrel1, Wroot1, Wrel2, Wroot2,
                                     WT1rel, WT1root, WT2rel, WT2root);

  // Layer 0: Z = x@Wrel0 (bf16); agg mode 2 computes root-init inline
  proj0_k<<<(N_NODES * HID + 255) / 256, 256, 0, stream>>>(x, Wrel0, Z);
  agg_k<<<(N_NODES + 3) / 4, 256, 0, stream>>>(Z, row_ptr, esrc, HA, 2, x, Wroot0, brel0);
  // Layer 1
  gemm_mfma_k<<<GEMM_NBLK, 256, 0, stream>>>(HA, WT1rel, WT1root, brel1, Z, HB, 0);
  agg_k<<<(N_NODES + 3) / 4, 256, 0, stream>>>(Z, row_ptr, esrc, HB, 0, nullptr, nullptr, nullptr);
  // Layer 2: gemm -> Z (rel, bf16) + OUTF (root+bias, f32); fused agg+pool
  gemm_mfma_k<<<GEMM_NBLK, 256, 0, stream>>>(HB, WT2rel, WT2root, brel2, Z, OUTF, 1);
  pool_fused_k<<<(PNW + 3) / 4, 256, 0, stream>>>(Z, OUTF, row_ptr, esrc, batch, pool, cnt);

  final_k<<<(NGRAPH + 3) / 4, 256, 0, stream>>>(pool, cnt, Wlin, blin, out);
}

// Round 10
// 336.176 us; speedup vs baseline: 3.6774x; 1.0101x over previous
//
#include <hip/hip_runtime.h>
#include <hip/hip_bf16.h>
#include <math.h>

#define N_NODES 50000
#define N_EDGES 640000
#define IN_DIM 5
#define HID 128
#define NGRAPH 512
#define SCAN_NBLK ((N_NODES + 255) / 256)  // 196
#define GEMM_NBLK ((N_NODES + 63) / 64)    // 782
#define PCHUNK 8
#define PNW ((N_NODES + PCHUNK - 1) / PCHUNK)  // 6250

typedef unsigned short u16;
typedef __attribute__((ext_vector_type(8))) short bf16x8;
typedef __attribute__((ext_vector_type(8))) unsigned short u16x8;
typedef __attribute__((ext_vector_type(4))) float f32x4;
typedef __attribute__((ext_vector_type(8))) float f32x8;

__device__ __forceinline__ float bf2f(u16 u) {
  union { unsigned int i; float f; } v; v.i = ((unsigned int)u) << 16; return v.f;
}
__device__ __forceinline__ u16 f2bf(float f) {
  return __bfloat16_as_ushort(__float2bfloat16(f));
}

// ---------------- CSR build ----------------
__global__ void count_edges_k(const int* __restrict__ dst, int* __restrict__ counts) {
  int e = blockIdx.x * blockDim.x + threadIdx.x;
  if (e < N_EDGES) atomicAdd(&counts[dst[e]], 1);
}

__global__ __launch_bounds__(256) void partial_k(const int* __restrict__ counts,
                                                 int* __restrict__ bsum) {
  int t = threadIdx.x;
  int i = blockIdx.x * 256 + t;
  int v = (i < N_NODES) ? counts[i] : 0;
#pragma unroll
  for (int off = 32; off; off >>= 1) v += __shfl_down(v, off, 64);
  __shared__ int ws[4];
  if ((t & 63) == 0) ws[t >> 6] = v;
  __syncthreads();
  if (t == 0) bsum[blockIdx.x] = ws[0] + ws[1] + ws[2] + ws[3];
}

__global__ __launch_bounds__(256) void scanb_k(const int* __restrict__ bsum,
                                               int* __restrict__ boff,
                                               int* __restrict__ row_ptr) {
  __shared__ int s[256];
  int t = threadIdx.x;
  int v = (t < SCAN_NBLK) ? bsum[t] : 0;
  s[t] = v;
  __syncthreads();
#pragma unroll
  for (int off = 1; off < 256; off <<= 1) {
    int u = (t >= off) ? s[t - off] : 0;
    __syncthreads();
    s[t] += u;
    __syncthreads();
  }
  if (t < SCAN_NBLK) boff[t] = s[t] - v;
  if (t == 255) row_ptr[N_NODES] = s[255];
}

__global__ __launch_bounds__(256) void write_scan_k(const int* __restrict__ counts,
                                                    const int* __restrict__ boff,
                                                    int* __restrict__ row_ptr,
                                                    int* __restrict__ fill_off) {
  __shared__ int s[256];
  int t = threadIdx.x;
  int i = blockIdx.x * 256 + t;
  int c = (i < N_NODES) ? counts[i] : 0;
  s[t] = c;
  __syncthreads();
#pragma unroll
  for (int off = 1; off < 256; off <<= 1) {
    int u = (t >= off) ? s[t - off] : 0;
    __syncthreads();
    s[t] += u;
    __syncthreads();
  }
  int excl = s[t] - c + boff[blockIdx.x];
  if (i < N_NODES) {
    row_ptr[i] = excl;
    fill_off[i] = excl;
  }
}

__global__ void fill_edges_k(const int* __restrict__ src, const int* __restrict__ dst,
                             int* __restrict__ fill_off, int* __restrict__ esrc) {
  int e = blockIdx.x * blockDim.x + threadIdx.x;
  if (e < N_EDGES) {
    int d = dst[e];
    int pos = atomicAdd(&fill_off[d], 1);
    esrc[pos] = src[e];
  }
}

// ---------------- Weight prep: 4x (W f32 [k][n] -> WT bf16 [n][k]) in one launch ----
__global__ __launch_bounds__(256) void prep_w4_k(const float* __restrict__ W0,
                                                 const float* __restrict__ W1,
                                                 const float* __restrict__ W2,
                                                 const float* __restrict__ W3,
                                                 u16* __restrict__ T0, u16* __restrict__ T1,
                                                 u16* __restrict__ T2, u16* __restrict__ T3) {
  int which = blockIdx.x >> 6;
  int idx = (blockIdx.x & 63) * 256 + threadIdx.x;  // k*128 + n
  const float* W = which == 0 ? W0 : which == 1 ? W1 : which == 2 ? W2 : W3;
  u16* T = which == 0 ? T0 : which == 1 ? T1 : which == 2 ? T2 : T3;
  int k = idx >> 7, n = idx & 127;
  T[n * HID + k] = f2bf(W[idx]);
}

// ---------------- Layer 0 rel projection only (IN_DIM=5); Z bf16 ----------------
__global__ void proj0_k(const float* __restrict__ x, const float* __restrict__ Wrel,
                        u16* __restrict__ Z) {
  int idx = blockIdx.x * blockDim.x + threadIdx.x;  // node*128 + c
  if (idx >= N_NODES * HID) return;
  int i = idx >> 7, c = idx & 127;
  float zr = 0.f;
#pragma unroll
  for (int k = 0; k < IN_DIM; ++k) zr = fmaf(x[i * IN_DIM + k], Wrel[k * HID + c], zr);
  Z[idx] = f2bf(zr);
}

// ---------------- MFMA GEMM for layers 1,2 ----------------
__global__ __launch_bounds__(256, 3) void gemm_mfma_k(const u16* __restrict__ A,
                                                      const u16* __restrict__ WrelT,
                                                      const u16* __restrict__ WrootT,
                                                      const float* __restrict__ bias,
                                                      u16* __restrict__ Z,
                                                      void* __restrict__ R,
                                                      int r_is_f32) {
  __shared__ u16 As[64][136];  // pad +8 bf16 -> 2-way max bank aliasing (free)
  int tid = threadIdx.x;
  int wv = tid >> 6, lane = tid & 63;
  int m = lane & 15, quad = lane >> 4;
  int r0 = blockIdx.x * 64;

#pragma unroll
  for (int it = 0; it < 4; ++it) {
    int idx = it * 256 + tid;
    int row = idx >> 4, q = idx & 15;
    int grow = r0 + row;
    float4 v = make_float4(0.f, 0.f, 0.f, 0.f);
    if (grow < N_NODES) v = *(const float4*)(A + (size_t)grow * HID + q * 8);
    *(float4*)&As[row][q * 8] = v;
  }
  __syncthreads();

  const u16* WT = (wv < 2) ? WrelT : WrootT;
  int n0 = (wv & 1) * 64;

  f32x4 acc[4][4];
#pragma unroll
  for (int mt = 0; mt < 4; ++mt)
#pragma unroll
    for (int nt = 0; nt < 4; ++nt) acc[mt][nt] = (f32x4){0.f, 0.f, 0.f, 0.f};

#pragma unroll
  for (int ks = 0; ks < 4; ++ks) {
    int kb = ks * 32;
    bf16x8 af[4], bf[4];
#pragma unroll
    for (int mt = 0; mt < 4; ++mt)
      af[mt] = *(const bf16x8*)&As[mt * 16 + m][kb + quad * 8];
#pragma unroll
    for (int nt = 0; nt < 4; ++nt)
      bf[nt] = *(const bf16x8*)(WT + (size_t)(n0 + nt * 16 + m) * HID + kb + quad * 8);
#pragma unroll
    for (int mt = 0; mt < 4; ++mt)
#pragma unroll
      for (int nt = 0; nt < 4; ++nt)
        acc[mt][nt] = __builtin_amdgcn_mfma_f32_16x16x32_bf16(af[mt], bf[nt], acc[mt][nt], 0, 0, 0);
  }

  // Epilogue. C/D layout: col = lane&15, row = quad*4 + reg.
  if (wv < 2) {
#pragma unroll
    for (int mt = 0; mt < 4; ++mt) {
#pragma unroll
      for (int nt = 0; nt < 4; ++nt) {
        int col = n0 + nt * 16 + m;
#pragma unroll
        for (int r = 0; r < 4; ++r) {
          int row = r0 + mt * 16 + quad * 4 + r;
          if (row < N_NODES) Z[(size_t)row * HID + col] = f2bf(acc[mt][nt][r]);
        }
      }
    }
  } else {
    float bl[4];
#pragma unroll
    for (int nt = 0; nt < 4; ++nt) bl[nt] = bias[n0 + nt * 16 + m];
#pragma unroll
    for (int mt = 0; mt < 4; ++mt) {
#pragma unroll
      for (int nt = 0; nt < 4; ++nt) {
        int col = n0 + nt * 16 + m;
#pragma unroll
        for (int r = 0; r < 4; ++r) {
          int row = r0 + mt * 16 + quad * 4 + r;
          if (row < N_NODES) {
            float v = acc[mt][nt][r] + bl[nt];
            if (r_is_f32) ((float*)R)[(size_t)row * HID + col] = v;
            else          ((u16*)R)[(size_t)row * HID + col] = f2bf(v);
          }
        }
      }
    }
  }
}

// ---- gather helper: unrolled x2, 8 edges in flight per wave ----
__device__ __forceinline__ void gather_node(const u16* __restrict__ Z,
                                            const int* __restrict__ esrc,
                                            int beg, int end, int q, int f8,
                                            f32x8& out) {
  f32x8 a0, a1;
#pragma unroll
  for (int j = 0; j < 8; ++j) { a0[j] = 0.f; a1[j] = 0.f; }
  int e = beg + q;
  for (; e + 4 < end; e += 8) {
    int s0 = esrc[e];
    int s1 = esrc[e + 4];
    u16x8 za = *(const u16x8*)(Z + (size_t)s0 * HID + f8);
    u16x8 zb = *(const u16x8*)(Z + (size_t)s1 * HID + f8);
#pragma unroll
    for (int j = 0; j < 8; ++j) { a0[j] += bf2f(za[j]); a1[j] += bf2f(zb[j]); }
  }
  if (e < end) {
    int s0 = esrc[e];
    u16x8 za = *(const u16x8*)(Z + (size_t)s0 * HID + f8);
#pragma unroll
    for (int j = 0; j < 8; ++j) a0[j] += bf2f(za[j]);
  }
#pragma unroll
  for (int j = 0; j < 8; ++j) out[j] = a0[j] + a1[j];
}

// ---------------- Edge aggregation (layers 0,1), OUT bf16 + ReLU ----------------
// mode 0: OUT bf16 rmw + ReLU.  mode 2: OUT = relu(x@Wroot0 + b0 + gather).
__global__ __launch_bounds__(256) void agg_k(const u16* __restrict__ Z,
                                             const int* __restrict__ row_ptr,
                                             const int* __restrict__ esrc,
                                             u16* __restrict__ OUT, int mode,
                                             const float* __restrict__ x,
                                             const float* __restrict__ Wroot,
                                             const float* __restrict__ bias) {
  int wave = threadIdx.x >> 6;
  int lane = threadIdx.x & 63;
  int node = blockIdx.x * 4 + wave;
  if (node >= N_NODES) return;
  int q = lane >> 4;        // 0..3
  int f8 = (lane & 15) * 8; // 8 features/lane
  int beg = row_ptr[node], end = row_ptr[node + 1];
  f32x8 acc;
  gather_node(Z, esrc, beg, end, q, f8, acc);
#pragma unroll
  for (int j = 0; j < 8; ++j) {
    acc[j] += __shfl_xor(acc[j], 16, 64);
    acc[j] += __shfl_xor(acc[j], 32, 64);
  }
  if (q == 0) {
    u16* o = OUT + (size_t)node * HID + f8;
    u16x8 w8;
    if (mode == 0) {
      u16x8 o8 = *(const u16x8*)o;
#pragma unroll
      for (int j = 0; j < 8; ++j) w8[j] = f2bf(fmaxf(bf2f(o8[j]) + acc[j], 0.f));
    } else {
      float xr[IN_DIM];
#pragma unroll
      for (int k = 0; k < IN_DIM; ++k) xr[k] = x[node * IN_DIM + k];
#pragma unroll
      for (int j = 0; j < 8; ++j) {
        float r = bias[f8 + j];
#pragma unroll
        for (int k = 0; k < IN_DIM; ++k) r = fmaf(xr[k], Wroot[k * HID + f8 + j], r);
        w8[j] = f2bf(fmaxf(r + acc[j], 0.f));
      }
    }
    *(u16x8*)o = w8;
  }
}

// ---------------- Fused layer-2 agg + mean pool ----------------
// Quarter-private accumulators: NO per-node cross-quarter reduction (that was
// round 9's 59us mistake - a wave-wide shfl sync per node). Each quarter
// accumulates its gather partials across nodes; ROOT row added by quarter n&3;
// shfl reduction only at segment-boundary flush (~1 per chunk).
__global__ __launch_bounds__(256) void pool_fused_k(const u16* __restrict__ Z,
                                                    const float* __restrict__ ROOT,
                                                    const int* __restrict__ row_ptr,
                                                    const int* __restrict__ esrc,
                                                    const int* __restrict__ batch,
                                                    float* __restrict__ pool,
                                                    int* __restrict__ cnt) {
  int wave = blockIdx.x * 4 + (threadIdx.x >> 6);
  int lane = threadIdx.x & 63;
  if (wave >= PNW) return;
  int q = lane >> 4;
  int f8 = (lane & 15) * 8;
  int n0 = wave * PCHUNK;
  int n1 = n0 + PCHUNK;
  if (n1 > N_NODES) n1 = N_NODES;
  int cur = batch[n0];
  int run = 0;
  float pacc[8];
#pragma unroll
  for (int j = 0; j < 8; ++j) pacc[j] = 0.f;

  auto flush = [&](int g) {
#pragma unroll
    for (int j = 0; j < 8; ++j) {
      pacc[j] += __shfl_xor(pacc[j], 16, 64);
      pacc[j] += __shfl_xor(pacc[j], 32, 64);
    }
    if (q == 0) {
#pragma unroll
      for (int j = 0; j < 8; ++j) atomicAdd(&pool[(size_t)g * HID + f8 + j], pacc[j]);
    }
    if (lane == 0) atomicAdd(&cnt[g], run);
#pragma unroll
    for (int j = 0; j < 8; ++j) pacc[j] = 0.f;
    run = 0;
  };

  for (int n = n0; n < n1; ++n) {
    int g = batch[n];  // wave-uniform
    if (g != cur) { flush(cur); cur = g; }
    int beg = row_ptr[n], end = row_ptr[n + 1];
    f32x8 acc;
    gather_node(Z, esrc, beg, end, q, f8, acc);
#pragma unroll
    for (int j = 0; j < 8; ++j) pacc[j] += acc[j];
    if ((n & 3) == q) {
      const float* rp = ROOT + (size_t)n * HID + f8;
      float4 ra = *(const float4*)rp;
      float4 rb = *(const float4*)(rp + 4);
      pacc[0] += ra.x; pacc[1] += ra.y; pacc[2] += ra.z; pacc[3] += ra.w;
      pacc[4] += rb.x; pacc[5] += rb.y; pacc[6] += rb.z; pacc[7] += rb.w;
    }
    run += 1;
  }
  flush(cur);
}

// ---------------- Final: sigmoid(pool/cnt @ Wlin + b) ----------------
__global__ __launch_bounds__(256) void final_k(const float* __restrict__ pool,
                                               const int* __restrict__ cnt,
                                               const float* __restrict__ Wlin,
                                               const float* __restrict__ blin,
                                               float* __restrict__ out) {
  int wave = threadIdx.x >> 6;
  int lane = threadIdx.x & 63;
  int g = blockIdx.x * 4 + wave;
  if (g >= NGRAPH) return;
  float2 p = *(const float2*)&pool[(size_t)g * HID + lane * 2];
  float v = p.x * Wlin[lane * 2 + 0] + p.y * Wlin[lane * 2 + 1];
#pragma unroll
  for (int off = 32; off; off >>= 1) v += __shfl_down(v, off, 64);
  if (lane == 0) {
    float c = (float)cnt[g];
    if (c < 1.f) c = 1.f;
    float logit = v / c + blin[0];
    out[g] = 1.f / (1.f + expf(-logit));
  }
}

extern "C" void kernel_launch(void* const* d_in, const int* in_sizes, int n_in,
                              void* d_out, int out_size, void* d_ws, size_t ws_size,
                              hipStream_t stream) {
  const float* x      = (const float*)d_in[0];
  const int*   ei     = (const int*)d_in[1];
  const int*   batch  = (const int*)d_in[2];
  const float* Wrel0  = (const float*)d_in[3];
  const float* brel0  = (const float*)d_in[4];
  const float* Wroot0 = (const float*)d_in[5];
  const float* Wrel1  = (const float*)d_in[6];
  const float* brel1  = (const float*)d_in[7];
  const float* Wroot1 = (const float*)d_in[8];
  const float* Wrel2  = (const float*)d_in[9];
  const float* brel2  = (const float*)d_in[10];
  const float* Wroot2 = (const float*)d_in[11];
  const float* Wlin   = (const float*)d_in[12];
  const float* blin   = (const float*)d_in[13];
  float* out = (float*)d_out;
  const int* srcp = ei;
  const int* dstp = ei + N_EDGES;

  char* ws = (char*)d_ws;
  size_t off = 0;
  auto alloc = [&](size_t b) { size_t o = off; off += (b + 255) & ~(size_t)255; return o; };
  u16*  Z     = (u16*)(ws + alloc(sizeof(u16) * N_NODES * HID));
  u16*  HA    = (u16*)(ws + alloc(sizeof(u16) * N_NODES * HID));
  u16*  HB    = (u16*)(ws + alloc(sizeof(u16) * N_NODES * HID));
  float* OUTF = (float*)(ws + alloc(sizeof(float) * N_NODES * HID));
  u16* WT1rel = (u16*)(ws + alloc(sizeof(u16) * HID * HID));
  u16* WT1root= (u16*)(ws + alloc(sizeof(u16) * HID * HID));
  u16* WT2rel = (u16*)(ws + alloc(sizeof(u16) * HID * HID));
  u16* WT2root= (u16*)(ws + alloc(sizeof(u16) * HID * HID));
  int* row_ptr  = (int*)(ws + alloc(sizeof(int) * (N_NODES + 1)));
  int* esrc     = (int*)(ws + alloc(sizeof(int) * N_EDGES));
  int* fill_off = (int*)(ws + alloc(sizeof(int) * N_NODES));
  int* bsum     = (int*)(ws + alloc(sizeof(int) * 256));
  int* boff     = (int*)(ws + alloc(sizeof(int) * 256));
  size_t zero_base = off;
  int* counts  = (int*)(ws + alloc(sizeof(int) * N_NODES));
  float* pool  = (float*)(ws + alloc(sizeof(float) * NGRAPH * HID));
  int* cnt     = (int*)(ws + alloc(sizeof(int) * NGRAPH));
  size_t zero_len = off - zero_base;

  hipMemsetAsync(ws + zero_base, 0, zero_len, stream);

  count_edges_k<<<(N_EDGES + 255) / 256, 256, 0, stream>>>(dstp, counts);
  partial_k<<<SCAN_NBLK, 256, 0, stream>>>(counts, bsum);
  scanb_k<<<1, 256, 0, stream>>>(bsum, boff, row_ptr);
  write_scan_k<<<SCAN_NBLK, 256, 0, stream>>>(counts, boff, row_ptr, fill_off);
  fill_edges_k<<<(N_EDGES + 255) / 256, 256, 0, stream>>>(srcp, dstp, fill_off, esrc);

  prep_w4_k<<<256, 256, 0, stream>>>(Wrel1, Wroot1, Wrel2, Wroot2,
                                     WT1rel, WT1root, WT2rel, WT2root);

  // Layer 0: Z = x@Wrel0 (bf16); agg mode 2 computes root-init inline
  proj0_k<<<(N_NODES * HID + 255) / 256, 256, 0, stream>>>(x, Wrel0, Z);
  agg_k<<<(N_NODES + 3) / 4, 256, 0, stream>>>(Z, row_ptr, esrc, HA, 2, x, Wroot0, brel0);
  // Layer 1
  gemm_mfma_k<<<GEMM_NBLK, 256, 0, stream>>>(HA, WT1rel, WT1root, brel1, Z, HB, 0);
  agg_k<<<(N_NODES + 3) / 4, 256, 0, stream>>>(Z, row_ptr, esrc, HB, 0, nullptr, nullptr, nullptr);
  // Layer 2: gemm -> Z (rel, bf16) + OUTF (root+bias, f32); fused agg+pool
  gemm_mfma_k<<<GEMM_NBLK, 256, 0, stream>>>(HB, WT2rel, WT2root, brel2, Z, OUTF, 1);
  pool_fused_k<<<(PNW + 3) / 4, 256, 0, stream>>>(Z, OUTF, row_ptr, esrc, batch, pool, cnt);

  final_k<<<(NGRAPH + 3) / 4, 256, 0, stream>>>(pool, cnt, Wlin, blin, out);
}